// Round 16
// baseline (180.012 us; speedup 1.0000x reference)
//
#include <hip/hip_runtime.h>
#include <hip/hip_bf16.h>
#include <math.h>

// Problem constants (B=4, T=1024, C=768, E=8, K=2)
#define N_TOK 4096
#define CDIM  768
#define E_EXP 8
#define CAPC  2048
#define HDIM  3072   // 4*C

typedef __attribute__((ext_vector_type(8))) short short8;
typedef __attribute__((ext_vector_type(4))) float floatx4;

#define VMCNT(n) asm volatile("s_waitcnt vmcnt(" #n ")" ::: "memory")
#define LGKM(n)  asm volatile("s_waitcnt lgkmcnt(" #n ")" ::: "memory")
#define SB0()    __builtin_amdgcn_sched_barrier(0)

static __device__ __forceinline__ unsigned short f2bf(float f) {
  __hip_bfloat16 h = __float2bfloat16(f);
  return __builtin_bit_cast(unsigned short, h);
}
static __device__ __forceinline__ float bf2f(unsigned short u) {
  return __builtin_bit_cast(float, (unsigned int)u << 16);
}
static __device__ __forceinline__ unsigned int f2bf2(float a, float b) {
  return (unsigned int)f2bf(a) | ((unsigned int)f2bf(b) << 16);
}

// ---------------------------------------------------------------------------
// K1: fused prep — weight transposes into TILED bf16 layout + router.
// Tiled layout (round-12): W^T as [e][bx][kt][128 n][64 k] 16KB tiles; GEMM
// stage_b reads tile_base + kt*16384 + li*128 + kb.
// Block = [64 k][128 n], bf16 LDS tile [64][130] = 16.6KB -> 9 blocks/CU
// (vs r12's f32 33KB / 4 blocks/CU): 2.2x memory-level parallelism.
// Row stride 65 dwords (== 1 mod 32): both phases <=2-way bank (free).
// blockIdx partition: [0,2304) c_fc; [2304,4608) c_proj; [4608,5632) router.
// ---------------------------------------------------------------------------
__global__ __launch_bounds__(256)
void prep_kernel(const float* __restrict__ cfc, const float* __restrict__ cpr,
                 __hip_bfloat16* __restrict__ wfcT, __hip_bfloat16* __restrict__ wprT,
                 const float* __restrict__ x, const float* __restrict__ wg,
                 int* __restrict__ eidx, float* __restrict__ pval)
{
  __shared__ unsigned short tile[64][130];   // bf16 [k][n], 260B row (65 dw)
  const int b = blockIdx.x;
  const int t = threadIdx.x;
  if (b < 4608) {
    const float* src;
    unsigned short* dstT;
    int Cc;
    if (b < 2304) {
      // c_fc [E][768][3072]: e<8, kt<12, bx<24
      const int e = b / 288, rem = b % 288;
      const int kt = rem / 24, bx = rem % 24;
      src = cfc + (size_t)e * CDIM * HDIM + (size_t)(kt * 64) * HDIM + bx * 128;
      Cc = HDIM;
      dstT = (unsigned short*)wfcT + (((size_t)e * 24 + bx) * 12 + kt) * 8192;
    } else {
      // c_proj [E][3072][768]: e<8, kt<48, bx<6
      const int bb = b - 2304;
      const int e = bb / 288, rem = bb % 288;
      const int kt = rem / 6, bx = rem % 6;
      src = cpr + (size_t)e * HDIM * CDIM + (size_t)(kt * 64) * CDIM + bx * 128;
      Cc = CDIM;
      dstT = (unsigned short*)wprT + (((size_t)e * 6 + bx) * 48 + kt) * 8192;
    }
    // phase 1: 64 rows x 512B reads (4 threads/row, 8 float4 each);
    // convert f32->bf16 on the fly, write as u32 pairs (4B-aligned).
    {
      const int r = t >> 2, q = t & 3;
      const float* rowp = src + (size_t)r * Cc;
#pragma unroll
      for (int i = 0; i < 8; ++i) {
        const int n = q * 32 + i * 4;
        const float4 v = *(const float4*)(rowp + n);
        *(unsigned int*)&tile[r][n]     = f2bf2(v.x, v.y);
        *(unsigned int*)&tile[r][n + 2] = f2bf2(v.z, v.w);
      }
    }
    __syncthreads();
    // phase 2: emit one [128 n][64 k] 16KB tile; thread reads u32 (cols
    // np,np+1) over 16 k-rows -> writes 2x32B k-contiguous runs per col.
    {
      const int kq = (t & 3) * 16;
      const int np = (t >> 2) * 2;
      unsigned short lo[16], hi[16];
#pragma unroll
      for (int i = 0; i < 16; ++i) {
        const unsigned int u = *(const unsigned int*)&tile[kq + i][np];
        lo[i] = (unsigned short)u;
        hi[i] = (unsigned short)(u >> 16);
      }
      unsigned short* d0 = dstT + (size_t)np * 64 + kq;
      *(short8*)(d0)     = *(short8*)&lo[0];
      *(short8*)(d0 + 8) = *(short8*)&lo[8];
      unsigned short* d1 = d0 + 64;
      *(short8*)(d1)     = *(short8*)&hi[0];
      *(short8*)(d1 + 8) = *(short8*)&hi[8];
    }
  } else {
    // router: one wave per token
    const int wv = t >> 6, lane = t & 63;
    const int n = (b - 4608) * 4 + wv;
    const float* xr = x + (size_t)n * CDIM;
    float acc[E_EXP] = {0.f, 0.f, 0.f, 0.f, 0.f, 0.f, 0.f, 0.f};
#pragma unroll
    for (int i = 0; i < CDIM / 64; ++i) {
      const float xv = xr[i * 64 + lane];
#pragma unroll
      for (int e = 0; e < E_EXP; ++e)
        acc[e] = fmaf(xv, wg[e * CDIM + i * 64 + lane], acc[e]);
    }
#pragma unroll
    for (int e = 0; e < E_EXP; ++e) {
#pragma unroll
      for (int off = 32; off > 0; off >>= 1)
        acc[e] += __shfl_xor(acc[e], off);
    }
    if (lane == 0) {
      int e0 = 0; float v0 = acc[0];
#pragma unroll
      for (int e = 1; e < E_EXP; ++e) if (acc[e] > v0) { v0 = acc[e]; e0 = e; }
      int e1 = -1; float v1 = -3.4e38f;
#pragma unroll
      for (int e = 0; e < E_EXP; ++e) if (e != e0 && acc[e] > v1) { v1 = acc[e]; e1 = e; }
      const float ex = __expf(v1 - v0);
      const float inv = 1.f / (1.f + ex);
      eidx[n] = e0; eidx[N_TOK + n] = e1;
      pval[n] = inv; pval[N_TOK + n] = ex * inv;
    }
  }
}

// ---------------------------------------------------------------------------
// K4: capacity scan (k-major reference order), single block Hillis-Steele.
// Emits ecnt[e] and a compact 128-row-tile work list shared by both GEMMs.
// ---------------------------------------------------------------------------
__global__ __launch_bounds__(256)
void scan_kernel(const int* __restrict__ eidx, int* __restrict__ slot,
                 int* __restrict__ slot_token, int* __restrict__ ecnt,
                 int* __restrict__ work2, int* __restrict__ wcnt)
{
  const int t = threadIdx.x;
  const int base = t * 32;
  int e_local[32];
  int cnt[E_EXP] = {0, 0, 0, 0, 0, 0, 0, 0};
#pragma unroll
  for (int i = 0; i < 32; ++i) {
    const int e = eidx[base + i];
    e_local[i] = e;
    cnt[e]++;
  }
  __shared__ int hist[256][E_EXP];
  __shared__ int secnt[E_EXP];
#pragma unroll
  for (int e = 0; e < E_EXP; ++e) hist[t][e] = cnt[e];
  __syncthreads();
  for (int off = 1; off < 256; off <<= 1) {
    int v[E_EXP] = {0, 0, 0, 0, 0, 0, 0, 0};
    if (t >= off) {
#pragma unroll
      for (int e = 0; e < E_EXP; ++e) v[e] = hist[t - off][e];
    }
    __syncthreads();
    if (t >= off) {
#pragma unroll
      for (int e = 0; e < E_EXP; ++e) hist[t][e] += v[e];
    }
    __syncthreads();
  }
  if (t == 255) {
#pragma unroll
    for (int e = 0; e < E_EXP; ++e) {
      const int tot = hist[255][e];
      const int c = tot < CAPC ? tot : CAPC;
      ecnt[e] = c;
      secnt[e] = c;
    }
  }
  __syncthreads();
  if (t == 0) {
    int n2 = 0;
    for (int e = 0; e < E_EXP; ++e) {
      const int c = secnt[e];
      const int t2 = (c + 127) >> 7;
      for (int b = 0; b < t2; ++b) work2[n2++] = (e << 8) | b;
    }
    wcnt[0] = n2 * 24;
    wcnt[1] = n2 * 6;
  }
  int run[E_EXP];
#pragma unroll
  for (int e = 0; e < E_EXP; ++e) run[e] = hist[t][e] - cnt[e];
#pragma unroll
  for (int i = 0; i < 32; ++i) {
    const int a = base + i;
    const int e = e_local[i];
    const int r = run[e]++;
    const int s = (r < CAPC) ? r : -1;
    slot[a] = s;
    if (s >= 0) slot_token[e * CAPC + s] = (a < N_TOK) ? a : (a - N_TOK);
  }
}

// ---------------------------------------------------------------------------
// K5: dispatch — exp_in row = bf16(x[token]) for used slots only.
// ---------------------------------------------------------------------------
__global__ __launch_bounds__(256)
void dispatch_kernel(const float* __restrict__ x, const int* __restrict__ slot_token,
                     const int* __restrict__ ecnt, __hip_bfloat16* __restrict__ xin)
{
  const int wv = threadIdx.x >> 6, lane = threadIdx.x & 63;
  const int s = blockIdx.x * 4 + wv;
  const int e = s >> 11;                 // CAPC = 2048
  if ((s & (CAPC - 1)) >= ecnt[e]) return;
  const int n = slot_token[s];
  unsigned short* orow = (unsigned short*)xin + (size_t)s * CDIM;
  const float4* xr = (const float4*)(x + (size_t)n * CDIM);
#pragma unroll
  for (int i = 0; i < 3; ++i) {
    const float4 v = xr[i * 64 + lane];
    ushort4 o;
    o.x = f2bf(v.x); o.y = f2bf(v.y); o.z = f2bf(v.z); o.w = f2bf(v.w);
    *(ushort4*)(orow + (size_t)(i * 64 + lane) * 4) = o;
  }
}

// ---------------------------------------------------------------------------
// K6 core: 128x128-tile GEMM body, BK=64, 4 waves (2Mx2N), dbuf 64 KiB,
// counted vmcnt + counted LGKM (proven round-5..12 body).
// A: row-major [slot][K]; B: tiled [bx][kt][128][64] (16KB tiles).
// ---------------------------------------------------------------------------
__device__ __forceinline__ void stage_a(const __hip_bfloat16* Ae, char* lds,
                                        int K, int kt, int wv, int lane)
{
  char* dst = lds + (kt & 1) * 32768;
#pragma unroll
  for (int j = 0; j < 4; ++j) {
    const int li = j * 32 + wv * 8 + (lane >> 3);
    const int kb = ((lane & 7) * 16) ^ ((li & 7) << 4);
    const char* g = (const char*)Ae + ((size_t)li * K + (size_t)kt * 64) * 2 + kb;
    __builtin_amdgcn_global_load_lds((const __attribute__((address_space(1))) unsigned int*)g,
                                     (__attribute__((address_space(3))) unsigned int*)(dst + j * 4096 + wv * 1024),
                                     16, 0, 0);
  }
}
__device__ __forceinline__ void stage_b(const char* BeT, char* lds,
                                        int kt, int wv, int lane)
{
  char* dst = lds + (kt & 1) * 32768 + 16384;
#pragma unroll
  for (int j = 0; j < 4; ++j) {
    const int li = j * 32 + wv * 8 + (lane >> 3);
    const int kb = ((lane & 7) * 16) ^ ((li & 7) << 4);
    const char* g = BeT + (size_t)kt * 16384 + li * 128 + kb;
    __builtin_amdgcn_global_load_lds((const __attribute__((address_space(1))) unsigned int*)g,
                                     (__attribute__((address_space(3))) unsigned int*)(dst + j * 4096 + wv * 1024),
                                     16, 0, 0);
  }
}

template<int VME, bool S2>
__device__ __forceinline__ void ktile2(int kt, char* lds,
                                       const __hip_bfloat16* Ae, const char* BeT,
                                       int K, floatx4 (&acc)[4][4],
                                       int wm, int wn, int fr, int fk, int wv, int lane)
{
  if constexpr (VME == 8) VMCNT(8); else VMCNT(0);
  __builtin_amdgcn_s_barrier();
  SB0();
  const char* bufA = lds + ((kt & 1) ? 32768 : 0);
  const char* bufB = bufA + 16384;
  short8 a[4][2], b[4][2];
#pragma unroll
  for (int mi = 0; mi < 4; ++mi) {
    const int lr = wm * 64 + mi * 16 + fr;
    a[mi][0] = *(const short8*)(bufA + lr * 128 + ((fk * 16) ^ ((lr & 7) << 4)));
  }
#pragma unroll
  for (int ni = 0; ni < 4; ++ni) {
    const int lj = wn * 64 + ni * 16 + fr;
    b[ni][0] = *(const short8*)(bufB + lj * 128 + ((fk * 16) ^ ((lj & 7) << 4)));
  }
  SB0();
#pragma unroll
  for (int mi = 0; mi < 4; ++mi) {
    const int lr = wm * 64 + mi * 16 + fr;
    a[mi][1] = *(const short8*)(bufA + lr * 128 + ((64 + fk * 16) ^ ((lr & 7) << 4)));
  }
#pragma unroll
  for (int ni = 0; ni < 4; ++ni) {
    const int lj = wn * 64 + ni * 16 + fr;
    b[ni][1] = *(const short8*)(bufB + lj * 128 + ((64 + fk * 16) ^ ((lj & 7) << 4)));
  }
  SB0();
  LGKM(8); SB0();
  __builtin_amdgcn_s_setprio(1);
#pragma unroll
  for (int mi = 0; mi < 4; ++mi)
#pragma unroll
    for (int ni = 0; ni < 4; ++ni)
      acc[mi][ni] = __builtin_amdgcn_mfma_f32_16x16x32_bf16(a[mi][0], b[ni][0], acc[mi][ni], 0, 0, 0);
  __builtin_amdgcn_s_setprio(0);
  SB0();
  LGKM(0); SB0();
  __builtin_amdgcn_s_setprio(1);
#pragma unroll
  for (int mi = 0; mi < 4; ++mi)
#pragma unroll
    for (int ni = 0; ni < 4; ++ni)
      acc[mi][ni] = __builtin_amdgcn_mfma_f32_16x16x32_bf16(a[mi][1], b[ni][1], acc[mi][ni], 0, 0, 0);
  __builtin_amdgcn_s_setprio(0);
  SB0();
  __builtin_amdgcn_s_barrier();
  if (S2) {
    stage_a(Ae, lds, K, kt + 2, wv, lane);
    stage_b(BeT, lds, kt + 2, wv, lane);
  }
  SB0();
}

// fast exact-grade GELU: tanh form, |err| ~3e-4 << bf16 rounding of the output
static __device__ __forceinline__ float gelu_fast(float v) {
  const float u2 = v * (1.5957691216f + 0.0713548163f * v * v);
  const float ez = __expf(u2);
  return v * ez / (ez + 1.0f);
}

// Shared epilogue: LDS-staged coalesced bf16 store (wave-private 2KB region).
template<int EPI>
__device__ __forceinline__ void epilogue_bf16(floatx4 (&acc)[4][4], char* lds,
                                              const float* be, unsigned short* Cb,
                                              int Nn, int m0, int n0,
                                              int wm, int wn, int fr, int fk,
                                              int wv, int lane)
{
  unsigned short* ep = (unsigned short*)(lds + wv * 2048);
  float bcol[4];
#pragma unroll
  for (int ni = 0; ni < 4; ++ni) bcol[ni] = be[n0 + wn * 64 + ni * 16 + fr];
#pragma unroll
  for (int mi = 0; mi < 4; ++mi) {
#pragma unroll
    for (int ni = 0; ni < 4; ++ni)
#pragma unroll
      for (int j = 0; j < 4; ++j) {
        float v = acc[mi][ni][j] + bcol[ni];
        if (EPI == 1) v = gelu_fast(v);
        const int row = fk * 4 + j;
        *(unsigned short*)((char*)ep + row * 128 + ((ni * 32 + fr * 2) ^ (fk << 5))) = f2bf(v);
      }
    LGKM(0); SB0();
    const int r = lane & 15;
    const int grow = m0 + wm * 64 + mi * 16 + r;
#pragma unroll
    for (int it = 0; it < 2; ++it) {
      const int q = (lane >> 4) + it * 4;
      const short8 vv = *(const short8*)((char*)ep + r * 128 + ((q * 16) ^ ((r >> 2) << 5)));
      *(short8*)(Cb + (size_t)grow * Nn + n0 + wn * 64 + q * 8) = vv;
    }
    LGKM(0); SB0();
  }
}

// ---------------------------------------------------------------------------
// K6a: GEMM1 persistent — grid 512 (2 blocks/CU); each block loops over its
// XCD-chunked share of the work list.  B tiled: [e][bx<24][kt<12][128][64].
// ---------------------------------------------------------------------------
__global__ __launch_bounds__(256, 2)
void gemm1p(const __hip_bfloat16* __restrict__ A, const __hip_bfloat16* __restrict__ Bt,
            const float* __restrict__ bias, __hip_bfloat16* __restrict__ Cout,
            const int* __restrict__ work, const int* __restrict__ wcnt)
{
  extern __shared__ __align__(16) char lds[];
  const int T = wcnt[0];
  const int cpx = (T + 7) >> 3;
  const int x8 = blockIdx.x & 7, l = blockIdx.x >> 3;
  const int lim = (x8 + 1) * cpx < T ? (x8 + 1) * cpx : T;

  const int t = threadIdx.x, wv = t >> 6, lane = t & 63;
  const int wm = wv >> 1, wn = wv & 1;
  const int fr = lane & 15, fk = lane >> 4;
  constexpr int ntk = CDIM / 64;   // 12

  for (int i = x8 * cpx + l; i < lim; i += 64) {
    const int p = i / 24;
    const int bx0 = i % 24;
    const int bx = (p & 1) ? (23 - bx0) : bx0;          // serpentine for L2 reuse
    const int w = work[p];
    const int e = w >> 8, by = w & 255;

    const __hip_bfloat16* Ae = A + (size_t)e * CAPC * CDIM + (size_t)by * 128 * CDIM;
    const char* BeT = (const char*)Bt + (((size_t)e * 24 + bx) * 12) * 16384;

    floatx4 acc[4][4] = {};

    stage_a(Ae, lds, CDIM, 0, wv, lane);
    stage_b(BeT, lds, 0, wv, lane);
    stage_a(Ae, lds, CDIM, 1, wv, lane);
    stage_b(BeT, lds, 1, wv, lane);
    SB0();

#pragma unroll 1
    for (int kt = 0; kt < ntk - 2; ++kt)
      ktile2<8, true>(kt, lds, Ae, BeT, CDIM, acc, wm, wn, fr, fk, wv, lane);
    ktile2<8, false>(ntk - 2, lds, Ae, BeT, CDIM, acc, wm, wn, fr, fk, wv, lane);
    ktile2<0, false>(ntk - 1, lds, Ae, BeT, CDIM, acc, wm, wn, fr, fk, wv, lane);

    epilogue_bf16<1>(acc, lds,
                     bias + (size_t)e * HDIM,
                     (unsigned short*)Cout + (size_t)e * CAPC * HDIM,
                     HDIM, by * 128, bx * 128, wm, wn, fr, fk, wv, lane);
    __builtin_amdgcn_s_barrier();   // all waves done with LDS epilogue regions
    SB0();
  }
}

// ---------------------------------------------------------------------------
// K6b: GEMM2 — single round; B tiled: [e][bx<6][kt<48][128][64].
// ---------------------------------------------------------------------------
__global__ __launch_bounds__(256, 2)
void gemm2x(const __hip_bfloat16* __restrict__ A, const __hip_bfloat16* __restrict__ Bt,
            const float* __restrict__ bias, __hip_bfloat16* __restrict__ Cout,
            const int* __restrict__ work, const int* __restrict__ wcnt)
{
  extern __shared__ __align__(16) char lds[];
  const int T = wcnt[1];
  const int bId = blockIdx.x;
  const int cpx = (T + 7) >> 3;
  if ((bId >> 3) >= cpx) return;
  const int idx = (bId & 7) * cpx + (bId >> 3);
  if (idx >= T) return;
  const int p = idx / 6;
  const int bx0 = idx % 6;
  const int bx = (p & 1) ? (5 - bx0) : bx0;
  const int w = work[p];
  const int e = w >> 8, by = w & 255;

  const int t = threadIdx.x, wv = t >> 6, lane = t & 63;
  const int wm = wv >> 1, wn = wv & 1;
  const int fr = lane & 15, fk = lane >> 4;
  constexpr int ntk = HDIM / 64;   // 48

  const __hip_bfloat16* Ae = A + (size_t)e * CAPC * HDIM + (size_t)by * 128 * HDIM;
  const char* BeT = (const char*)Bt + (((size_t)e * 6 + bx) * 48) * 16384;

  floatx4 acc[4][4] = {};

  stage_a(Ae, lds, HDIM, 0, wv, lane);
  stage_b(BeT, lds, 0, wv, lane);
  stage_a(Ae, lds, HDIM, 1, wv, lane);
  stage_b(BeT, lds, 1, wv, lane);
  SB0();

#pragma unroll 1
  for (int kt = 0; kt < ntk - 2; ++kt)
    ktile2<8, true>(kt, lds, Ae, BeT, HDIM, acc, wm, wn, fr, fk, wv, lane);
  ktile2<8, false>(ntk - 2, lds, Ae, BeT, HDIM, acc, wm, wn, fr, fk, wv, lane);
  ktile2<0, false>(ntk - 1, lds, Ae, BeT, HDIM, acc, wm, wn, fr, fk, wv, lane);

  epilogue_bf16<2>(acc, lds,
                   bias + (size_t)e * CDIM,
                   (unsigned short*)Cout + (size_t)e * CAPC * CDIM,
                   CDIM, by * 128, bx * 128, wm, wn, fr, fk, wv, lane);
}

// ---------------------------------------------------------------------------
// K7: combine — out[n] = w0*exp_out[e0][s0] + w1*exp_out[e1][s1], bf16 eout.
// ---------------------------------------------------------------------------
__global__ __launch_bounds__(256)
void combine_kernel(const __hip_bfloat16* __restrict__ eout, const int* __restrict__ eidx,
                    const float* __restrict__ pval, const int* __restrict__ slot,
                    float* __restrict__ out)
{
  const int wv = threadIdx.x >> 6, lane = threadIdx.x & 63;
  const int n = blockIdx.x * 4 + wv;
  const int e0 = eidx[n], e1 = eidx[N_TOK + n];
  int s0 = slot[n], s1 = slot[N_TOK + n];
  const float w0 = (s0 >= 0) ? pval[n] : 0.f;
  const float w1 = (s1 >= 0) ? pval[N_TOK + n] : 0.f;
  s0 = (s0 >= 0) ? s0 : 0;
  s1 = (s1 >= 0) ? s1 : 0;
  const ushort4* r0 = (const ushort4*)((const unsigned short*)eout + ((size_t)e0 * CAPC + s0) * CDIM);
  const ushort4* r1 = (const ushort4*)((const unsigned short*)eout + ((size_t)e1 * CAPC + s1) * CDIM);
  float4* o = (float4*)(out + (size_t)n * CDIM);
#pragma unroll
  for (int i = 0; i < 3; ++i) {
    const ushort4 a = r0[i * 64 + lane];
    const ushort4 b = r1[i * 64 + lane];
    float4 c;
    c.x = w0 * bf2f(a.x) + w1 * bf2f(b.x);
    c.y = w0 * bf2f(a.y) + w1 * bf2f(b.y);
    c.z = w0 * bf2f(a.z) + w1 * bf2f(b.z);
    c.w = w0 * bf2f(a.w) + w1 * bf2f(b.w);
    o[i * 64 + lane] = c;
  }
}

// ---------------------------------------------------------------------------
extern "C" void kernel_launch(void* const* d_in, const int* in_sizes, int n_in,
                              void* d_out, int out_size, void* d_ws, size_t ws_size,
                              hipStream_t stream)
{
  const float* x   = (const float*)d_in[0];
  const float* wg  = (const float*)d_in[1];
  const float* cfc = (const float*)d_in[2];
  const float* fcb = (const float*)d_in[3];
  const float* cpr = (const float*)d_in[4];
  const float* prb = (const float*)d_in[5];
  float* out = (float*)d_out;

  char* ws = (char*)d_ws;
  size_t off = 0;
  auto take = [&](size_t bytes) -> void* {
    void* p = ws + off;
    off += (bytes + 255) & ~(size_t)255;
    return p;
  };
  __hip_bfloat16* wfcT = (__hip_bfloat16*)take((size_t)E_EXP * HDIM * CDIM * 2); // tiled [e][24][12][128][64]
  __hip_bfloat16* wprT = (__hip_bfloat16*)take((size_t)E_EXP * CDIM * HDIM * 2); // tiled [e][6][48][128][64]
  __hip_bfloat16* xin  = (__hip_bfloat16*)take((size_t)E_EXP * CAPC * CDIM * 2); // [E][CAP][768]
  __hip_bfloat16* hbuf = (__hip_bfloat16*)take((size_t)E_EXP * CAPC * HDIM * 2); // [E][CAP][3072]
  __hip_bfloat16* eout = (__hip_bfloat16*)take((size_t)E_EXP * CAPC * CDIM * 2); // [E][CAP][768] bf16
  int*   eidx = (int*)take((size_t)2 * N_TOK * 4);
  float* pv   = (float*)take((size_t)2 * N_TOK * 4);
  int*   slot = (int*)take((size_t)2 * N_TOK * 4);
  int*   stok = (int*)take((size_t)E_EXP * CAPC * 4);
  int*   ecnt = (int*)take((size_t)E_EXP * 4);
  int*   work2 = (int*)take((size_t)128 * 4);
  int*   wcnt = (int*)take((size_t)2 * 4);

  hipFuncSetAttribute((const void*)gemm1p,
                      hipFuncAttributeMaxDynamicSharedMemorySize, 65536);
  hipFuncSetAttribute((const void*)gemm2x,
                      hipFuncAttributeMaxDynamicSharedMemorySize, 65536);

  // fused prep: tiled weight transposes (bf16 LDS, 9 blocks/CU) + router
  prep_kernel<<<4608 + 1024, 256, 0, stream>>>(cfc, cpr, wfcT, wprT, x, wg, eidx, pv);
  scan_kernel<<<1, 256, 0, stream>>>(eidx, slot, stok, ecnt, work2, wcnt);
  dispatch_kernel<<<(E_EXP * CAPC) / 4, 256, 0, stream>>>(x, stok, ecnt, xin);

  // GEMM1 + bias + GELU -> h (bf16): persistent 512 blocks (2/CU), work-looped.
  gemm1p<<<512, 256, 65536, stream>>>(xin, wfcT, fcb, hbuf, work2, wcnt);
  // GEMM2 + bias -> eout (bf16): single round, <=768 active blocks.
  gemm2x<<<768, 256, 65536, stream>>>(hbuf, wprT, prb, eout, work2, wcnt);

  combine_kernel<<<N_TOK / 4, 256, 0, stream>>>(eout, eidx, pv, slot, out);
}

// Round 17
// 173.418 us; speedup vs baseline: 1.0380x; 1.0380x over previous
//
#include <hip/hip_runtime.h>
#include <hip/hip_bf16.h>
#include <math.h>

// Problem constants (B=4, T=1024, C=768, E=8, K=2)
#define N_TOK 4096
#define CDIM  768
#define E_EXP 8
#define CAPC  2048
#define HDIM  3072   // 4*C

typedef __attribute__((ext_vector_type(8))) short short8;
typedef __attribute__((ext_vector_type(4))) float floatx4;

#define VMCNT(n) asm volatile("s_waitcnt vmcnt(" #n ")" ::: "memory")
#define LGKM(n)  asm volatile("s_waitcnt lgkmcnt(" #n ")" ::: "memory")
#define SB0()    __builtin_amdgcn_sched_barrier(0)

static __device__ __forceinline__ unsigned short f2bf(float f) {
  __hip_bfloat16 h = __float2bfloat16(f);
  return __builtin_bit_cast(unsigned short, h);
}
static __device__ __forceinline__ float bf2f(unsigned short u) {
  return __builtin_bit_cast(float, (unsigned int)u << 16);
}

// ---------------------------------------------------------------------------
// K1: fused prep — LDS-FREE weight transpose into tiled bf16 layout + router.
// Tiled layout (round-12): W^T as [e][bx][kt][128 n][64 k] 16KB tiles; GEMM
// stage_b reads tile_base + kt*16384 + li*128 + kb.
// Per block: one [64 k][128 n] tile.  Thread (nq=t&31, ko=t>>5) reads 8
// float4 down column-quad nq (per wave-instr: 512B contiguous row segment),
// converts in regs, writes 4x 16B contiguous short8 (one per n-col).
// No LDS, no __syncthreads -> occupancy VGPR-bound, deep MLP.
// blockIdx partition: [0,2304) c_fc; [2304,4608) c_proj; [4608,5632) router.
// ---------------------------------------------------------------------------
__global__ __launch_bounds__(256)
void prep_kernel(const float* __restrict__ cfc, const float* __restrict__ cpr,
                 __hip_bfloat16* __restrict__ wfcT, __hip_bfloat16* __restrict__ wprT,
                 const float* __restrict__ x, const float* __restrict__ wg,
                 int* __restrict__ eidx, float* __restrict__ pval)
{
  const int b = blockIdx.x;
  const int t = threadIdx.x;
  if (b < 4608) {
    const float* src;
    unsigned short* dstT;
    int Cc;
    if (b < 2304) {
      // c_fc [E][768][3072]: e<8, kt<12, bx<24
      const int e = b / 288, rem = b % 288;
      const int kt = rem / 24, bx = rem % 24;
      src = cfc + (size_t)e * CDIM * HDIM + (size_t)(kt * 64) * HDIM + bx * 128;
      Cc = HDIM;
      dstT = (unsigned short*)wfcT + (((size_t)e * 24 + bx) * 12 + kt) * 8192;
    } else {
      // c_proj [E][3072][768]: e<8, kt<48, bx<6
      const int bb = b - 2304;
      const int e = bb / 288, rem = bb % 288;
      const int kt = rem / 6, bx = rem % 6;
      src = cpr + (size_t)e * HDIM * CDIM + (size_t)(kt * 64) * CDIM + bx * 128;
      Cc = CDIM;
      dstT = (unsigned short*)wprT + (((size_t)e * 6 + bx) * 48 + kt) * 8192;
    }
    const int nq = t & 31, ko = t >> 5;          // column-quad, k-octet
    const float* colp = src + (size_t)(ko * 8) * Cc + nq * 4;
    unsigned short obuf[4][8];                   // [c][j], static indexing
#pragma unroll
    for (int j = 0; j < 8; ++j) {
      const float4 v = *(const float4*)(colp + (size_t)j * Cc);
      obuf[0][j] = f2bf(v.x); obuf[1][j] = f2bf(v.y);
      obuf[2][j] = f2bf(v.z); obuf[3][j] = f2bf(v.w);
    }
#pragma unroll
    for (int c = 0; c < 4; ++c)
      *(short8*)(dstT + (size_t)(nq * 4 + c) * 64 + ko * 8) = *(short8*)&obuf[c][0];
  } else {
    // router: one wave per token
    const int wv = t >> 6, lane = t & 63;
    const int n = (b - 4608) * 4 + wv;
    const float* xr = x + (size_t)n * CDIM;
    float acc[E_EXP] = {0.f, 0.f, 0.f, 0.f, 0.f, 0.f, 0.f, 0.f};
#pragma unroll
    for (int i = 0; i < CDIM / 64; ++i) {
      const float xv = xr[i * 64 + lane];
#pragma unroll
      for (int e = 0; e < E_EXP; ++e)
        acc[e] = fmaf(xv, wg[e * CDIM + i * 64 + lane], acc[e]);
    }
#pragma unroll
    for (int e = 0; e < E_EXP; ++e) {
#pragma unroll
      for (int off = 32; off > 0; off >>= 1)
        acc[e] += __shfl_xor(acc[e], off);
    }
    if (lane == 0) {
      int e0 = 0; float v0 = acc[0];
#pragma unroll
      for (int e = 1; e < E_EXP; ++e) if (acc[e] > v0) { v0 = acc[e]; e0 = e; }
      int e1 = -1; float v1 = -3.4e38f;
#pragma unroll
      for (int e = 0; e < E_EXP; ++e) if (e != e0 && acc[e] > v1) { v1 = acc[e]; e1 = e; }
      const float ex = __expf(v1 - v0);
      const float inv = 1.f / (1.f + ex);
      eidx[n] = e0; eidx[N_TOK + n] = e1;
      pval[n] = inv; pval[N_TOK + n] = ex * inv;
    }
  }
}

// ---------------------------------------------------------------------------
// K4: capacity scan (k-major reference order), single block Hillis-Steele.
// Emits ecnt[e] and a compact 128-row-tile work list shared by both GEMMs.
// ---------------------------------------------------------------------------
__global__ __launch_bounds__(256)
void scan_kernel(const int* __restrict__ eidx, int* __restrict__ slot,
                 int* __restrict__ slot_token, int* __restrict__ ecnt,
                 int* __restrict__ work2, int* __restrict__ wcnt)
{
  const int t = threadIdx.x;
  const int base = t * 32;
  int e_local[32];
  int cnt[E_EXP] = {0, 0, 0, 0, 0, 0, 0, 0};
#pragma unroll
  for (int i = 0; i < 32; ++i) {
    const int e = eidx[base + i];
    e_local[i] = e;
    cnt[e]++;
  }
  __shared__ int hist[256][E_EXP];
  __shared__ int secnt[E_EXP];
#pragma unroll
  for (int e = 0; e < E_EXP; ++e) hist[t][e] = cnt[e];
  __syncthreads();
  for (int off = 1; off < 256; off <<= 1) {
    int v[E_EXP] = {0, 0, 0, 0, 0, 0, 0, 0};
    if (t >= off) {
#pragma unroll
      for (int e = 0; e < E_EXP; ++e) v[e] = hist[t - off][e];
    }
    __syncthreads();
    if (t >= off) {
#pragma unroll
      for (int e = 0; e < E_EXP; ++e) hist[t][e] += v[e];
    }
    __syncthreads();
  }
  if (t == 255) {
#pragma unroll
    for (int e = 0; e < E_EXP; ++e) {
      const int tot = hist[255][e];
      const int c = tot < CAPC ? tot : CAPC;
      ecnt[e] = c;
      secnt[e] = c;
    }
  }
  __syncthreads();
  if (t == 0) {
    int n2 = 0;
    for (int e = 0; e < E_EXP; ++e) {
      const int c = secnt[e];
      const int t2 = (c + 127) >> 7;
      for (int b = 0; b < t2; ++b) work2[n2++] = (e << 8) | b;
    }
    wcnt[0] = n2 * 24;
    wcnt[1] = n2 * 6;
  }
  int run[E_EXP];
#pragma unroll
  for (int e = 0; e < E_EXP; ++e) run[e] = hist[t][e] - cnt[e];
#pragma unroll
  for (int i = 0; i < 32; ++i) {
    const int a = base + i;
    const int e = e_local[i];
    const int r = run[e]++;
    const int s = (r < CAPC) ? r : -1;
    slot[a] = s;
    if (s >= 0) slot_token[e * CAPC + s] = (a < N_TOK) ? a : (a - N_TOK);
  }
}

// ---------------------------------------------------------------------------
// K5: dispatch — exp_in row = bf16(x[token]) for used slots only.
// ---------------------------------------------------------------------------
__global__ __launch_bounds__(256)
void dispatch_kernel(const float* __restrict__ x, const int* __restrict__ slot_token,
                     const int* __restrict__ ecnt, __hip_bfloat16* __restrict__ xin)
{
  const int wv = threadIdx.x >> 6, lane = threadIdx.x & 63;
  const int s = blockIdx.x * 4 + wv;
  const int e = s >> 11;                 // CAPC = 2048
  if ((s & (CAPC - 1)) >= ecnt[e]) return;
  const int n = slot_token[s];
  unsigned short* orow = (unsigned short*)xin + (size_t)s * CDIM;
  const float4* xr = (const float4*)(x + (size_t)n * CDIM);
#pragma unroll
  for (int i = 0; i < 3; ++i) {
    const float4 v = xr[i * 64 + lane];
    ushort4 o;
    o.x = f2bf(v.x); o.y = f2bf(v.y); o.z = f2bf(v.z); o.w = f2bf(v.w);
    *(ushort4*)(orow + (size_t)(i * 64 + lane) * 4) = o;
  }
}

// ---------------------------------------------------------------------------
// K6 core: 128x128-tile GEMM body, BK=64, 4 waves (2Mx2N), dbuf 64 KiB,
// counted vmcnt + counted LGKM (proven round-5..16 body).
// A: row-major [slot][K]; B: tiled [bx][kt][128][64] (16KB tiles).
// ---------------------------------------------------------------------------
__device__ __forceinline__ void stage_a(const __hip_bfloat16* Ae, char* lds,
                                        int K, int kt, int wv, int lane)
{
  char* dst = lds + (kt & 1) * 32768;
#pragma unroll
  for (int j = 0; j < 4; ++j) {
    const int li = j * 32 + wv * 8 + (lane >> 3);
    const int kb = ((lane & 7) * 16) ^ ((li & 7) << 4);
    const char* g = (const char*)Ae + ((size_t)li * K + (size_t)kt * 64) * 2 + kb;
    __builtin_amdgcn_global_load_lds((const __attribute__((address_space(1))) unsigned int*)g,
                                     (__attribute__((address_space(3))) unsigned int*)(dst + j * 4096 + wv * 1024),
                                     16, 0, 0);
  }
}
__device__ __forceinline__ void stage_b(const char* BeT, char* lds,
                                        int kt, int wv, int lane)
{
  char* dst = lds + (kt & 1) * 32768 + 16384;
#pragma unroll
  for (int j = 0; j < 4; ++j) {
    const int li = j * 32 + wv * 8 + (lane >> 3);
    const int kb = ((lane & 7) * 16) ^ ((li & 7) << 4);
    const char* g = BeT + (size_t)kt * 16384 + li * 128 + kb;
    __builtin_amdgcn_global_load_lds((const __attribute__((address_space(1))) unsigned int*)g,
                                     (__attribute__((address_space(3))) unsigned int*)(dst + j * 4096 + wv * 1024),
                                     16, 0, 0);
  }
}

template<int VME, bool S2>
__device__ __forceinline__ void ktile2(int kt, char* lds,
                                       const __hip_bfloat16* Ae, const char* BeT,
                                       int K, floatx4 (&acc)[4][4],
                                       int wm, int wn, int fr, int fk, int wv, int lane)
{
  if constexpr (VME == 8) VMCNT(8); else VMCNT(0);
  __builtin_amdgcn_s_barrier();
  SB0();
  const char* bufA = lds + ((kt & 1) ? 32768 : 0);
  const char* bufB = bufA + 16384;
  short8 a[4][2], b[4][2];
#pragma unroll
  for (int mi = 0; mi < 4; ++mi) {
    const int lr = wm * 64 + mi * 16 + fr;
    a[mi][0] = *(const short8*)(bufA + lr * 128 + ((fk * 16) ^ ((lr & 7) << 4)));
  }
#pragma unroll
  for (int ni = 0; ni < 4; ++ni) {
    const int lj = wn * 64 + ni * 16 + fr;
    b[ni][0] = *(const short8*)(bufB + lj * 128 + ((fk * 16) ^ ((lj & 7) << 4)));
  }
  SB0();
#pragma unroll
  for (int mi = 0; mi < 4; ++mi) {
    const int lr = wm * 64 + mi * 16 + fr;
    a[mi][1] = *(const short8*)(bufA + lr * 128 + ((64 + fk * 16) ^ ((lr & 7) << 4)));
  }
#pragma unroll
  for (int ni = 0; ni < 4; ++ni) {
    const int lj = wn * 64 + ni * 16 + fr;
    b[ni][1] = *(const short8*)(bufB + lj * 128 + ((64 + fk * 16) ^ ((lj & 7) << 4)));
  }
  SB0();
  LGKM(8); SB0();
  __builtin_amdgcn_s_setprio(1);
#pragma unroll
  for (int mi = 0; mi < 4; ++mi)
#pragma unroll
    for (int ni = 0; ni < 4; ++ni)
      acc[mi][ni] = __builtin_amdgcn_mfma_f32_16x16x32_bf16(a[mi][0], b[ni][0], acc[mi][ni], 0, 0, 0);
  __builtin_amdgcn_s_setprio(0);
  SB0();
  LGKM(0); SB0();
  __builtin_amdgcn_s_setprio(1);
#pragma unroll
  for (int mi = 0; mi < 4; ++mi)
#pragma unroll
    for (int ni = 0; ni < 4; ++ni)
      acc[mi][ni] = __builtin_amdgcn_mfma_f32_16x16x32_bf16(a[mi][1], b[ni][1], acc[mi][ni], 0, 0, 0);
  __builtin_amdgcn_s_setprio(0);
  SB0();
  __builtin_amdgcn_s_barrier();
  if (S2) {
    stage_a(Ae, lds, K, kt + 2, wv, lane);
    stage_b(BeT, lds, kt + 2, wv, lane);
  }
  SB0();
}

// fast exact-grade GELU: tanh form, |err| ~3e-4 << bf16 rounding of the output
static __device__ __forceinline__ float gelu_fast(float v) {
  const float u2 = v * (1.5957691216f + 0.0713548163f * v * v);
  const float ez = __expf(u2);
  return v * ez / (ez + 1.0f);
}

// Shared epilogue: LDS-staged coalesced bf16 store (wave-private 2KB region).
template<int EPI>
__device__ __forceinline__ void epilogue_bf16(floatx4 (&acc)[4][4], char* lds,
                                              const float* be, unsigned short* Cb,
                                              int Nn, int m0, int n0,
                                              int wm, int wn, int fr, int fk,
                                              int wv, int lane)
{
  unsigned short* ep = (unsigned short*)(lds + wv * 2048);
  float bcol[4];
#pragma unroll
  for (int ni = 0; ni < 4; ++ni) bcol[ni] = be[n0 + wn * 64 + ni * 16 + fr];
#pragma unroll
  for (int mi = 0; mi < 4; ++mi) {
#pragma unroll
    for (int ni = 0; ni < 4; ++ni)
#pragma unroll
      for (int j = 0; j < 4; ++j) {
        float v = acc[mi][ni][j] + bcol[ni];
        if (EPI == 1) v = gelu_fast(v);
        const int row = fk * 4 + j;
        *(unsigned short*)((char*)ep + row * 128 + ((ni * 32 + fr * 2) ^ (fk << 5))) = f2bf(v);
      }
    LGKM(0); SB0();
    const int r = lane & 15;
    const int grow = m0 + wm * 64 + mi * 16 + r;
#pragma unroll
    for (int it = 0; it < 2; ++it) {
      const int q = (lane >> 4) + it * 4;
      const short8 vv = *(const short8*)((char*)ep + r * 128 + ((q * 16) ^ ((r >> 2) << 5)));
      *(short8*)(Cb + (size_t)grow * Nn + n0 + wn * 64 + q * 8) = vv;
    }
    LGKM(0); SB0();
  }
}

// ---------------------------------------------------------------------------
// K6a: GEMM1 persistent — grid 512 (2 blocks/CU); each block loops over its
// XCD-chunked share of the work list.  B tiled: [e][bx<24][kt<12][128][64].
// ---------------------------------------------------------------------------
__global__ __launch_bounds__(256, 2)
void gemm1p(const __hip_bfloat16* __restrict__ A, const __hip_bfloat16* __restrict__ Bt,
            const float* __restrict__ bias, __hip_bfloat16* __restrict__ Cout,
            const int* __restrict__ work, const int* __restrict__ wcnt)
{
  extern __shared__ __align__(16) char lds[];
  const int T = wcnt[0];
  const int cpx = (T + 7) >> 3;
  const int x8 = blockIdx.x & 7, l = blockIdx.x >> 3;
  const int lim = (x8 + 1) * cpx < T ? (x8 + 1) * cpx : T;

  const int t = threadIdx.x, wv = t >> 6, lane = t & 63;
  const int wm = wv >> 1, wn = wv & 1;
  const int fr = lane & 15, fk = lane >> 4;
  constexpr int ntk = CDIM / 64;   // 12

  for (int i = x8 * cpx + l; i < lim; i += 64) {
    const int p = i / 24;
    const int bx0 = i % 24;
    const int bx = (p & 1) ? (23 - bx0) : bx0;          // serpentine for L2 reuse
    const int w = work[p];
    const int e = w >> 8, by = w & 255;

    const __hip_bfloat16* Ae = A + (size_t)e * CAPC * CDIM + (size_t)by * 128 * CDIM;
    const char* BeT = (const char*)Bt + (((size_t)e * 24 + bx) * 12) * 16384;

    floatx4 acc[4][4] = {};

    stage_a(Ae, lds, CDIM, 0, wv, lane);
    stage_b(BeT, lds, 0, wv, lane);
    stage_a(Ae, lds, CDIM, 1, wv, lane);
    stage_b(BeT, lds, 1, wv, lane);
    SB0();

#pragma unroll 1
    for (int kt = 0; kt < ntk - 2; ++kt)
      ktile2<8, true>(kt, lds, Ae, BeT, CDIM, acc, wm, wn, fr, fk, wv, lane);
    ktile2<8, false>(ntk - 2, lds, Ae, BeT, CDIM, acc, wm, wn, fr, fk, wv, lane);
    ktile2<0, false>(ntk - 1, lds, Ae, BeT, CDIM, acc, wm, wn, fr, fk, wv, lane);

    epilogue_bf16<1>(acc, lds,
                     bias + (size_t)e * HDIM,
                     (unsigned short*)Cout + (size_t)e * CAPC * HDIM,
                     HDIM, by * 128, bx * 128, wm, wn, fr, fk, wv, lane);
    __builtin_amdgcn_s_barrier();   // all waves done with LDS epilogue regions
    SB0();
  }
}

// ---------------------------------------------------------------------------
// K6b: GEMM2 — single round; B tiled: [e][bx<6][kt<48][128][64].
// ---------------------------------------------------------------------------
__global__ __launch_bounds__(256, 2)
void gemm2x(const __hip_bfloat16* __restrict__ A, const __hip_bfloat16* __restrict__ Bt,
            const float* __restrict__ bias, __hip_bfloat16* __restrict__ Cout,
            const int* __restrict__ work, const int* __restrict__ wcnt)
{
  extern __shared__ __align__(16) char lds[];
  const int T = wcnt[1];
  const int bId = blockIdx.x;
  const int cpx = (T + 7) >> 3;
  if ((bId >> 3) >= cpx) return;
  const int idx = (bId & 7) * cpx + (bId >> 3);
  if (idx >= T) return;
  const int p = idx / 6;
  const int bx0 = idx % 6;
  const int bx = (p & 1) ? (5 - bx0) : bx0;
  const int w = work[p];
  const int e = w >> 8, by = w & 255;

  const int t = threadIdx.x, wv = t >> 6, lane = t & 63;
  const int wm = wv >> 1, wn = wv & 1;
  const int fr = lane & 15, fk = lane >> 4;
  constexpr int ntk = HDIM / 64;   // 48

  const __hip_bfloat16* Ae = A + (size_t)e * CAPC * HDIM + (size_t)by * 128 * HDIM;
  const char* BeT = (const char*)Bt + (((size_t)e * 6 + bx) * 48) * 16384;

  floatx4 acc[4][4] = {};

  stage_a(Ae, lds, HDIM, 0, wv, lane);
  stage_b(BeT, lds, 0, wv, lane);
  stage_a(Ae, lds, HDIM, 1, wv, lane);
  stage_b(BeT, lds, 1, wv, lane);
  SB0();

#pragma unroll 1
  for (int kt = 0; kt < ntk - 2; ++kt)
    ktile2<8, true>(kt, lds, Ae, BeT, HDIM, acc, wm, wn, fr, fk, wv, lane);
  ktile2<8, false>(ntk - 2, lds, Ae, BeT, HDIM, acc, wm, wn, fr, fk, wv, lane);
  ktile2<0, false>(ntk - 1, lds, Ae, BeT, HDIM, acc, wm, wn, fr, fk, wv, lane);

  epilogue_bf16<2>(acc, lds,
                   bias + (size_t)e * CDIM,
                   (unsigned short*)Cout + (size_t)e * CAPC * CDIM,
                   CDIM, by * 128, bx * 128, wm, wn, fr, fk, wv, lane);
}

// ---------------------------------------------------------------------------
// K7: combine — out[n] = w0*exp_out[e0][s0] + w1*exp_out[e1][s1], bf16 eout.
// ---------------------------------------------------------------------------
__global__ __launch_bounds__(256)
void combine_kernel(const __hip_bfloat16* __restrict__ eout, const int* __restrict__ eidx,
                    const float* __restrict__ pval, const int* __restrict__ slot,
                    float* __restrict__ out)
{
  const int wv = threadIdx.x >> 6, lane = threadIdx.x & 63;
  const int n = blockIdx.x * 4 + wv;
  const int e0 = eidx[n], e1 = eidx[N_TOK + n];
  int s0 = slot[n], s1 = slot[N_TOK + n];
  const float w0 = (s0 >= 0) ? pval[n] : 0.f;
  const float w1 = (s1 >= 0) ? pval[N_TOK + n] : 0.f;
  s0 = (s0 >= 0) ? s0 : 0;
  s1 = (s1 >= 0) ? s1 : 0;
  const ushort4* r0 = (const ushort4*)((const unsigned short*)eout + ((size_t)e0 * CAPC + s0) * CDIM);
  const ushort4* r1 = (const ushort4*)((const unsigned short*)eout + ((size_t)e1 * CAPC + s1) * CDIM);
  float4* o = (float4*)(out + (size_t)n * CDIM);
#pragma unroll
  for (int i = 0; i < 3; ++i) {
    const ushort4 a = r0[i * 64 + lane];
    const ushort4 b = r1[i * 64 + lane];
    float4 c;
    c.x = w0 * bf2f(a.x) + w1 * bf2f(b.x);
    c.y = w0 * bf2f(a.y) + w1 * bf2f(b.y);
    c.z = w0 * bf2f(a.z) + w1 * bf2f(b.z);
    c.w = w0 * bf2f(a.w) + w1 * bf2f(b.w);
    o[i * 64 + lane] = c;
  }
}

// ---------------------------------------------------------------------------
extern "C" void kernel_launch(void* const* d_in, const int* in_sizes, int n_in,
                              void* d_out, int out_size, void* d_ws, size_t ws_size,
                              hipStream_t stream)
{
  const float* x   = (const float*)d_in[0];
  const float* wg  = (const float*)d_in[1];
  const float* cfc = (const float*)d_in[2];
  const float* fcb = (const float*)d_in[3];
  const float* cpr = (const float*)d_in[4];
  const float* prb = (const float*)d_in[5];
  float* out = (float*)d_out;

  char* ws = (char*)d_ws;
  size_t off = 0;
  auto take = [&](size_t bytes) -> void* {
    void* p = ws + off;
    off += (bytes + 255) & ~(size_t)255;
    return p;
  };
  __hip_bfloat16* wfcT = (__hip_bfloat16*)take((size_t)E_EXP * HDIM * CDIM * 2); // tiled [e][24][12][128][64]
  __hip_bfloat16* wprT = (__hip_bfloat16*)take((size_t)E_EXP * CDIM * HDIM * 2); // tiled [e][6][48][128][64]
  __hip_bfloat16* xin  = (__hip_bfloat16*)take((size_t)E_EXP * CAPC * CDIM * 2); // [E][CAP][768]
  __hip_bfloat16* hbuf = (__hip_bfloat16*)take((size_t)E_EXP * CAPC * HDIM * 2); // [E][CAP][3072]
  __hip_bfloat16* eout = (__hip_bfloat16*)take((size_t)E_EXP * CAPC * CDIM * 2); // [E][CAP][768] bf16
  int*   eidx = (int*)take((size_t)2 * N_TOK * 4);
  float* pv   = (float*)take((size_t)2 * N_TOK * 4);
  int*   slot = (int*)take((size_t)2 * N_TOK * 4);
  int*   stok = (int*)take((size_t)E_EXP * CAPC * 4);
  int*   ecnt = (int*)take((size_t)E_EXP * 4);
  int*   work2 = (int*)take((size_t)128 * 4);
  int*   wcnt = (int*)take((size_t)2 * 4);

  hipFuncSetAttribute((const void*)gemm1p,
                      hipFuncAttributeMaxDynamicSharedMemorySize, 65536);
  hipFuncSetAttribute((const void*)gemm2x,
                      hipFuncAttributeMaxDynamicSharedMemorySize, 65536);

  // fused prep: LDS-free tiled weight transposes + router
  prep_kernel<<<4608 + 1024, 256, 0, stream>>>(cfc, cpr, wfcT, wprT, x, wg, eidx, pv);
  scan_kernel<<<1, 256, 0, stream>>>(eidx, slot, stok, ecnt, work2, wcnt);
  dispatch_kernel<<<(E_EXP * CAPC) / 4, 256, 0, stream>>>(x, stok, ecnt, xin);

  // GEMM1 + bias + GELU -> h (bf16): persistent 512 blocks (2/CU), work-looped.
  gemm1p<<<512, 256, 65536, stream>>>(xin, wfcT, fcb, hbuf, work2, wcnt);
  // GEMM2 + bias -> eout (bf16): single round, <=768 active blocks.
  gemm2x<<<768, 256, 65536, stream>>>(hbuf, wprT, prb, eout, work2, wcnt);

  combine_kernel<<<N_TOK / 4, 256, 0, stream>>>(eout, eidx, pv, slot, out);
}

// Round 18
// 171.074 us; speedup vs baseline: 1.0522x; 1.0137x over previous
//
#include <hip/hip_runtime.h>
#include <hip/hip_bf16.h>
#include <math.h>

// Problem constants (B=4, T=1024, C=768, E=8, K=2)
#define N_TOK 4096
#define CDIM  768
#define E_EXP 8
#define CAPC  2048
#define HDIM  3072   // 4*C

typedef __attribute__((ext_vector_type(8))) short short8;
typedef __attribute__((ext_vector_type(4))) float floatx4;

#define VMCNT(n) asm volatile("s_waitcnt vmcnt(" #n ")" ::: "memory")
#define LGKM(n)  asm volatile("s_waitcnt lgkmcnt(" #n ")" ::: "memory")
#define SB0()    __builtin_amdgcn_sched_barrier(0)

static __device__ __forceinline__ unsigned short f2bf(float f) {
  __hip_bfloat16 h = __float2bfloat16(f);
  return __builtin_bit_cast(unsigned short, h);
}
static __device__ __forceinline__ float bf2f(unsigned short u) {
  return __builtin_bit_cast(float, (unsigned int)u << 16);
}

// ---------------------------------------------------------------------------
// K1: fused prep — LDS-free weight transpose into tiled bf16 layout + router.
// Round-17 structure + NON-TEMPORAL weight reads (nt flag): weights are L3-
// resident between graph replays and all six prep variants pinned at ~2.1TB/s;
// nt streams reads from HBM (~6.3TB/s) instead of the slower L3-serve path.
// Tiled layout: W^T as [e][bx][kt][128 n][64 k] 16KB tiles; GEMM stage_b
// reads tile_base + kt*16384 + li*128 + kb.
// blockIdx partition: [0,2304) c_fc; [2304,4608) c_proj; [4608,5632) router.
// ---------------------------------------------------------------------------
__global__ __launch_bounds__(256)
void prep_kernel(const float* __restrict__ cfc, const float* __restrict__ cpr,
                 __hip_bfloat16* __restrict__ wfcT, __hip_bfloat16* __restrict__ wprT,
                 const float* __restrict__ x, const float* __restrict__ wg,
                 int* __restrict__ eidx, float* __restrict__ pval)
{
  const int b = blockIdx.x;
  const int t = threadIdx.x;
  if (b < 4608) {
    const float* src;
    unsigned short* dstT;
    int Cc;
    if (b < 2304) {
      // c_fc [E][768][3072]: e<8, kt<12, bx<24
      const int e = b / 288, rem = b % 288;
      const int kt = rem / 24, bx = rem % 24;
      src = cfc + (size_t)e * CDIM * HDIM + (size_t)(kt * 64) * HDIM + bx * 128;
      Cc = HDIM;
      dstT = (unsigned short*)wfcT + (((size_t)e * 24 + bx) * 12 + kt) * 8192;
    } else {
      // c_proj [E][3072][768]: e<8, kt<48, bx<6
      const int bb = b - 2304;
      const int e = bb / 288, rem = bb % 288;
      const int kt = rem / 6, bx = rem % 6;
      src = cpr + (size_t)e * HDIM * CDIM + (size_t)(kt * 64) * CDIM + bx * 128;
      Cc = CDIM;
      dstT = (unsigned short*)wprT + (((size_t)e * 6 + bx) * 48 + kt) * 8192;
    }
    const int nq = t & 31, ko = t >> 5;          // column-quad, k-octet
    const float* colp = src + (size_t)(ko * 8) * Cc + nq * 4;
    unsigned short obuf[4][8];                   // [c][j], static indexing
#pragma unroll
    for (int j = 0; j < 8; ++j) {
      const floatx4 v = __builtin_nontemporal_load((const floatx4*)(colp + (size_t)j * Cc));
      obuf[0][j] = f2bf(v[0]); obuf[1][j] = f2bf(v[1]);
      obuf[2][j] = f2bf(v[2]); obuf[3][j] = f2bf(v[3]);
    }
#pragma unroll
    for (int c = 0; c < 4; ++c)
      *(short8*)(dstT + (size_t)(nq * 4 + c) * 64 + ko * 8) = *(short8*)&obuf[c][0];
  } else {
    // router: one wave per token
    const int wv = t >> 6, lane = t & 63;
    const int n = (b - 4608) * 4 + wv;
    const float* xr = x + (size_t)n * CDIM;
    float acc[E_EXP] = {0.f, 0.f, 0.f, 0.f, 0.f, 0.f, 0.f, 0.f};
#pragma unroll
    for (int i = 0; i < CDIM / 64; ++i) {
      const float xv = xr[i * 64 + lane];
#pragma unroll
      for (int e = 0; e < E_EXP; ++e)
        acc[e] = fmaf(xv, wg[e * CDIM + i * 64 + lane], acc[e]);
    }
#pragma unroll
    for (int e = 0; e < E_EXP; ++e) {
#pragma unroll
      for (int off = 32; off > 0; off >>= 1)
        acc[e] += __shfl_xor(acc[e], off);
    }
    if (lane == 0) {
      int e0 = 0; float v0 = acc[0];
#pragma unroll
      for (int e = 1; e < E_EXP; ++e) if (acc[e] > v0) { v0 = acc[e]; e0 = e; }
      int e1 = -1; float v1 = -3.4e38f;
#pragma unroll
      for (int e = 0; e < E_EXP; ++e) if (e != e0 && acc[e] > v1) { v1 = acc[e]; e1 = e; }
      const float ex = __expf(v1 - v0);
      const float inv = 1.f / (1.f + ex);
      eidx[n] = e0; eidx[N_TOK + n] = e1;
      pval[n] = inv; pval[N_TOK + n] = ex * inv;
    }
  }
}

// ---------------------------------------------------------------------------
// K4: capacity scan (k-major reference order), single block Hillis-Steele.
// Emits ecnt[e] and a compact 128-row-tile work list shared by both GEMMs.
// ---------------------------------------------------------------------------
__global__ __launch_bounds__(256)
void scan_kernel(const int* __restrict__ eidx, int* __restrict__ slot,
                 int* __restrict__ slot_token, int* __restrict__ ecnt,
                 int* __restrict__ work2, int* __restrict__ wcnt)
{
  const int t = threadIdx.x;
  const int base = t * 32;
  int e_local[32];
  int cnt[E_EXP] = {0, 0, 0, 0, 0, 0, 0, 0};
#pragma unroll
  for (int i = 0; i < 32; ++i) {
    const int e = eidx[base + i];
    e_local[i] = e;
    cnt[e]++;
  }
  __shared__ int hist[256][E_EXP];
  __shared__ int secnt[E_EXP];
#pragma unroll
  for (int e = 0; e < E_EXP; ++e) hist[t][e] = cnt[e];
  __syncthreads();
  for (int off = 1; off < 256; off <<= 1) {
    int v[E_EXP] = {0, 0, 0, 0, 0, 0, 0, 0};
    if (t >= off) {
#pragma unroll
      for (int e = 0; e < E_EXP; ++e) v[e] = hist[t - off][e];
    }
    __syncthreads();
    if (t >= off) {
#pragma unroll
      for (int e = 0; e < E_EXP; ++e) hist[t][e] += v[e];
    }
    __syncthreads();
  }
  if (t == 255) {
#pragma unroll
    for (int e = 0; e < E_EXP; ++e) {
      const int tot = hist[255][e];
      const int c = tot < CAPC ? tot : CAPC;
      ecnt[e] = c;
      secnt[e] = c;
    }
  }
  __syncthreads();
  if (t == 0) {
    int n2 = 0;
    for (int e = 0; e < E_EXP; ++e) {
      const int c = secnt[e];
      const int t2 = (c + 127) >> 7;
      for (int b = 0; b < t2; ++b) work2[n2++] = (e << 8) | b;
    }
    wcnt[0] = n2 * 24;
    wcnt[1] = n2 * 6;
  }
  int run[E_EXP];
#pragma unroll
  for (int e = 0; e < E_EXP; ++e) run[e] = hist[t][e] - cnt[e];
#pragma unroll
  for (int i = 0; i < 32; ++i) {
    const int a = base + i;
    const int e = e_local[i];
    const int r = run[e]++;
    const int s = (r < CAPC) ? r : -1;
    slot[a] = s;
    if (s >= 0) slot_token[e * CAPC + s] = (a < N_TOK) ? a : (a - N_TOK);
  }
}

// ---------------------------------------------------------------------------
// K5: dispatch — exp_in row = bf16(x[token]) for used slots only.
// ---------------------------------------------------------------------------
__global__ __launch_bounds__(256)
void dispatch_kernel(const float* __restrict__ x, const int* __restrict__ slot_token,
                     const int* __restrict__ ecnt, __hip_bfloat16* __restrict__ xin)
{
  const int wv = threadIdx.x >> 6, lane = threadIdx.x & 63;
  const int s = blockIdx.x * 4 + wv;
  const int e = s >> 11;                 // CAPC = 2048
  if ((s & (CAPC - 1)) >= ecnt[e]) return;
  const int n = slot_token[s];
  unsigned short* orow = (unsigned short*)xin + (size_t)s * CDIM;
  const float4* xr = (const float4*)(x + (size_t)n * CDIM);
#pragma unroll
  for (int i = 0; i < 3; ++i) {
    const float4 v = xr[i * 64 + lane];
    ushort4 o;
    o.x = f2bf(v.x); o.y = f2bf(v.y); o.z = f2bf(v.z); o.w = f2bf(v.w);
    *(ushort4*)(orow + (size_t)(i * 64 + lane) * 4) = o;
  }
}

// ---------------------------------------------------------------------------
// K6 core: 128x128-tile GEMM body, BK=64, 4 waves (2Mx2N), dbuf 64 KiB,
// counted vmcnt + counted LGKM (proven round-5..17 body).
// A: row-major [slot][K]; B: tiled [bx][kt][128][64] (16KB tiles).
// ---------------------------------------------------------------------------
__device__ __forceinline__ void stage_a(const __hip_bfloat16* Ae, char* lds,
                                        int K, int kt, int wv, int lane)
{
  char* dst = lds + (kt & 1) * 32768;
#pragma unroll
  for (int j = 0; j < 4; ++j) {
    const int li = j * 32 + wv * 8 + (lane >> 3);
    const int kb = ((lane & 7) * 16) ^ ((li & 7) << 4);
    const char* g = (const char*)Ae + ((size_t)li * K + (size_t)kt * 64) * 2 + kb;
    __builtin_amdgcn_global_load_lds((const __attribute__((address_space(1))) unsigned int*)g,
                                     (__attribute__((address_space(3))) unsigned int*)(dst + j * 4096 + wv * 1024),
                                     16, 0, 0);
  }
}
__device__ __forceinline__ void stage_b(const char* BeT, char* lds,
                                        int kt, int wv, int lane)
{
  char* dst = lds + (kt & 1) * 32768 + 16384;
#pragma unroll
  for (int j = 0; j < 4; ++j) {
    const int li = j * 32 + wv * 8 + (lane >> 3);
    const int kb = ((lane & 7) * 16) ^ ((li & 7) << 4);
    const char* g = BeT + (size_t)kt * 16384 + li * 128 + kb;
    __builtin_amdgcn_global_load_lds((const __attribute__((address_space(1))) unsigned int*)g,
                                     (__attribute__((address_space(3))) unsigned int*)(dst + j * 4096 + wv * 1024),
                                     16, 0, 0);
  }
}

template<int VME, bool S2>
__device__ __forceinline__ void ktile2(int kt, char* lds,
                                       const __hip_bfloat16* Ae, const char* BeT,
                                       int K, floatx4 (&acc)[4][4],
                                       int wm, int wn, int fr, int fk, int wv, int lane)
{
  if constexpr (VME == 8) VMCNT(8); else VMCNT(0);
  __builtin_amdgcn_s_barrier();
  SB0();
  const char* bufA = lds + ((kt & 1) ? 32768 : 0);
  const char* bufB = bufA + 16384;
  short8 a[4][2], b[4][2];
#pragma unroll
  for (int mi = 0; mi < 4; ++mi) {
    const int lr = wm * 64 + mi * 16 + fr;
    a[mi][0] = *(const short8*)(bufA + lr * 128 + ((fk * 16) ^ ((lr & 7) << 4)));
  }
#pragma unroll
  for (int ni = 0; ni < 4; ++ni) {
    const int lj = wn * 64 + ni * 16 + fr;
    b[ni][0] = *(const short8*)(bufB + lj * 128 + ((fk * 16) ^ ((lj & 7) << 4)));
  }
  SB0();
#pragma unroll
  for (int mi = 0; mi < 4; ++mi) {
    const int lr = wm * 64 + mi * 16 + fr;
    a[mi][1] = *(const short8*)(bufA + lr * 128 + ((64 + fk * 16) ^ ((lr & 7) << 4)));
  }
#pragma unroll
  for (int ni = 0; ni < 4; ++ni) {
    const int lj = wn * 64 + ni * 16 + fr;
    b[ni][1] = *(const short8*)(bufB + lj * 128 + ((64 + fk * 16) ^ ((lj & 7) << 4)));
  }
  SB0();
  LGKM(8); SB0();
  __builtin_amdgcn_s_setprio(1);
#pragma unroll
  for (int mi = 0; mi < 4; ++mi)
#pragma unroll
    for (int ni = 0; ni < 4; ++ni)
      acc[mi][ni] = __builtin_amdgcn_mfma_f32_16x16x32_bf16(a[mi][0], b[ni][0], acc[mi][ni], 0, 0, 0);
  __builtin_amdgcn_s_setprio(0);
  SB0();
  LGKM(0); SB0();
  __builtin_amdgcn_s_setprio(1);
#pragma unroll
  for (int mi = 0; mi < 4; ++mi)
#pragma unroll
    for (int ni = 0; ni < 4; ++ni)
      acc[mi][ni] = __builtin_amdgcn_mfma_f32_16x16x32_bf16(a[mi][1], b[ni][1], acc[mi][ni], 0, 0, 0);
  __builtin_amdgcn_s_setprio(0);
  SB0();
  __builtin_amdgcn_s_barrier();
  if (S2) {
    stage_a(Ae, lds, K, kt + 2, wv, lane);
    stage_b(BeT, lds, kt + 2, wv, lane);
  }
  SB0();
}

// fast exact-grade GELU: tanh form, |err| ~3e-4 << bf16 rounding of the output
static __device__ __forceinline__ float gelu_fast(float v) {
  const float u2 = v * (1.5957691216f + 0.0713548163f * v * v);
  const float ez = __expf(u2);
  return v * ez / (ez + 1.0f);
}

// Shared epilogue: LDS-staged coalesced bf16 store (wave-private 2KB region).
template<int EPI>
__device__ __forceinline__ void epilogue_bf16(floatx4 (&acc)[4][4], char* lds,
                                              const float* be, unsigned short* Cb,
                                              int Nn, int m0, int n0,
                                              int wm, int wn, int fr, int fk,
                                              int wv, int lane)
{
  unsigned short* ep = (unsigned short*)(lds + wv * 2048);
  float bcol[4];
#pragma unroll
  for (int ni = 0; ni < 4; ++ni) bcol[ni] = be[n0 + wn * 64 + ni * 16 + fr];
#pragma unroll
  for (int mi = 0; mi < 4; ++mi) {
#pragma unroll
    for (int ni = 0; ni < 4; ++ni)
#pragma unroll
      for (int j = 0; j < 4; ++j) {
        float v = acc[mi][ni][j] + bcol[ni];
        if (EPI == 1) v = gelu_fast(v);
        const int row = fk * 4 + j;
        *(unsigned short*)((char*)ep + row * 128 + ((ni * 32 + fr * 2) ^ (fk << 5))) = f2bf(v);
      }
    LGKM(0); SB0();
    const int r = lane & 15;
    const int grow = m0 + wm * 64 + mi * 16 + r;
#pragma unroll
    for (int it = 0; it < 2; ++it) {
      const int q = (lane >> 4) + it * 4;
      const short8 vv = *(const short8*)((char*)ep + r * 128 + ((q * 16) ^ ((r >> 2) << 5)));
      *(short8*)(Cb + (size_t)grow * Nn + n0 + wn * 64 + q * 8) = vv;
    }
    LGKM(0); SB0();
  }
}

// ---------------------------------------------------------------------------
// K6a: GEMM1 persistent — grid 512 (2 blocks/CU); each block loops over its
// XCD-chunked share of the work list.  B tiled: [e][bx<24][kt<12][128][64].
// ---------------------------------------------------------------------------
__global__ __launch_bounds__(256, 2)
void gemm1p(const __hip_bfloat16* __restrict__ A, const __hip_bfloat16* __restrict__ Bt,
            const float* __restrict__ bias, __hip_bfloat16* __restrict__ Cout,
            const int* __restrict__ work, const int* __restrict__ wcnt)
{
  extern __shared__ __align__(16) char lds[];
  const int T = wcnt[0];
  const int cpx = (T + 7) >> 3;
  const int x8 = blockIdx.x & 7, l = blockIdx.x >> 3;
  const int lim = (x8 + 1) * cpx < T ? (x8 + 1) * cpx : T;

  const int t = threadIdx.x, wv = t >> 6, lane = t & 63;
  const int wm = wv >> 1, wn = wv & 1;
  const int fr = lane & 15, fk = lane >> 4;
  constexpr int ntk = CDIM / 64;   // 12

  for (int i = x8 * cpx + l; i < lim; i += 64) {
    const int p = i / 24;
    const int bx0 = i % 24;
    const int bx = (p & 1) ? (23 - bx0) : bx0;          // serpentine for L2 reuse
    const int w = work[p];
    const int e = w >> 8, by = w & 255;

    const __hip_bfloat16* Ae = A + (size_t)e * CAPC * CDIM + (size_t)by * 128 * CDIM;
    const char* BeT = (const char*)Bt + (((size_t)e * 24 + bx) * 12) * 16384;

    floatx4 acc[4][4] = {};

    stage_a(Ae, lds, CDIM, 0, wv, lane);
    stage_b(BeT, lds, 0, wv, lane);
    stage_a(Ae, lds, CDIM, 1, wv, lane);
    stage_b(BeT, lds, 1, wv, lane);
    SB0();

#pragma unroll 1
    for (int kt = 0; kt < ntk - 2; ++kt)
      ktile2<8, true>(kt, lds, Ae, BeT, CDIM, acc, wm, wn, fr, fk, wv, lane);
    ktile2<8, false>(ntk - 2, lds, Ae, BeT, CDIM, acc, wm, wn, fr, fk, wv, lane);
    ktile2<0, false>(ntk - 1, lds, Ae, BeT, CDIM, acc, wm, wn, fr, fk, wv, lane);

    epilogue_bf16<1>(acc, lds,
                     bias + (size_t)e * HDIM,
                     (unsigned short*)Cout + (size_t)e * CAPC * HDIM,
                     HDIM, by * 128, bx * 128, wm, wn, fr, fk, wv, lane);
    __builtin_amdgcn_s_barrier();   // all waves done with LDS epilogue regions
    SB0();
  }
}

// ---------------------------------------------------------------------------
// K6b: GEMM2 — single round; B tiled: [e][bx<6][kt<48][128][64].
// ---------------------------------------------------------------------------
__global__ __launch_bounds__(256, 2)
void gemm2x(const __hip_bfloat16* __restrict__ A, const __hip_bfloat16* __restrict__ Bt,
            const float* __restrict__ bias, __hip_bfloat16* __restrict__ Cout,
            const int* __restrict__ work, const int* __restrict__ wcnt)
{
  extern __shared__ __align__(16) char lds[];
  const int T = wcnt[1];
  const int bId = blockIdx.x;
  const int cpx = (T + 7) >> 3;
  if ((bId >> 3) >= cpx) return;
  const int idx = (bId & 7) * cpx + (bId >> 3);
  if (idx >= T) return;
  const int p = idx / 6;
  const int bx0 = idx % 6;
  const int bx = (p & 1) ? (5 - bx0) : bx0;
  const int w = work[p];
  const int e = w >> 8, by = w & 255;

  const int t = threadIdx.x, wv = t >> 6, lane = t & 63;
  const int wm = wv >> 1, wn = wv & 1;
  const int fr = lane & 15, fk = lane >> 4;
  constexpr int ntk = HDIM / 64;   // 48

  const __hip_bfloat16* Ae = A + (size_t)e * CAPC * HDIM + (size_t)by * 128 * HDIM;
  const char* BeT = (const char*)Bt + (((size_t)e * 6 + bx) * 48) * 16384;

  floatx4 acc[4][4] = {};

  stage_a(Ae, lds, HDIM, 0, wv, lane);
  stage_b(BeT, lds, 0, wv, lane);
  stage_a(Ae, lds, HDIM, 1, wv, lane);
  stage_b(BeT, lds, 1, wv, lane);
  SB0();

#pragma unroll 1
  for (int kt = 0; kt < ntk - 2; ++kt)
    ktile2<8, true>(kt, lds, Ae, BeT, HDIM, acc, wm, wn, fr, fk, wv, lane);
  ktile2<8, false>(ntk - 2, lds, Ae, BeT, HDIM, acc, wm, wn, fr, fk, wv, lane);
  ktile2<0, false>(ntk - 1, lds, Ae, BeT, HDIM, acc, wm, wn, fr, fk, wv, lane);

  epilogue_bf16<2>(acc, lds,
                   bias + (size_t)e * CDIM,
                   (unsigned short*)Cout + (size_t)e * CAPC * CDIM,
                   CDIM, by * 128, bx * 128, wm, wn, fr, fk, wv, lane);
}

// ---------------------------------------------------------------------------
// K7: combine — out[n] = w0*exp_out[e0][s0] + w1*exp_out[e1][s1], bf16 eout.
// ---------------------------------------------------------------------------
__global__ __launch_bounds__(256)
void combine_kernel(const __hip_bfloat16* __restrict__ eout, const int* __restrict__ eidx,
                    const float* __restrict__ pval, const int* __restrict__ slot,
                    float* __restrict__ out)
{
  const int wv = threadIdx.x >> 6, lane = threadIdx.x & 63;
  const int n = blockIdx.x * 4 + wv;
  const int e0 = eidx[n], e1 = eidx[N_TOK + n];
  int s0 = slot[n], s1 = slot[N_TOK + n];
  const float w0 = (s0 >= 0) ? pval[n] : 0.f;
  const float w1 = (s1 >= 0) ? pval[N_TOK + n] : 0.f;
  s0 = (s0 >= 0) ? s0 : 0;
  s1 = (s1 >= 0) ? s1 : 0;
  const ushort4* r0 = (const ushort4*)((const unsigned short*)eout + ((size_t)e0 * CAPC + s0) * CDIM);
  const ushort4* r1 = (const ushort4*)((const unsigned short*)eout + ((size_t)e1 * CAPC + s1) * CDIM);
  float4* o = (float4*)(out + (size_t)n * CDIM);
#pragma unroll
  for (int i = 0; i < 3; ++i) {
    const ushort4 a = r0[i * 64 + lane];
    const ushort4 b = r1[i * 64 + lane];
    float4 c;
    c.x = w0 * bf2f(a.x) + w1 * bf2f(b.x);
    c.y = w0 * bf2f(a.y) + w1 * bf2f(b.y);
    c.z = w0 * bf2f(a.z) + w1 * bf2f(b.z);
    c.w = w0 * bf2f(a.w) + w1 * bf2f(b.w);
    o[i * 64 + lane] = c;
  }
}

// ---------------------------------------------------------------------------
extern "C" void kernel_launch(void* const* d_in, const int* in_sizes, int n_in,
                              void* d_out, int out_size, void* d_ws, size_t ws_size,
                              hipStream_t stream)
{
  const float* x   = (const float*)d_in[0];
  const float* wg  = (const float*)d_in[1];
  const float* cfc = (const float*)d_in[2];
  const float* fcb = (const float*)d_in[3];
  const float* cpr = (const float*)d_in[4];
  const float* prb = (const float*)d_in[5];
  float* out = (float*)d_out;

  char* ws = (char*)d_ws;
  size_t off = 0;
  auto take = [&](size_t bytes) -> void* {
    void* p = ws + off;
    off += (bytes + 255) & ~(size_t)255;
    return p;
  };
  __hip_bfloat16* wfcT = (__hip_bfloat16*)take((size_t)E_EXP * HDIM * CDIM * 2); // tiled [e][24][12][128][64]
  __hip_bfloat16* wprT = (__hip_bfloat16*)take((size_t)E_EXP * CDIM * HDIM * 2); // tiled [e][6][48][128][64]
  __hip_bfloat16* xin  = (__hip_bfloat16*)take((size_t)E_EXP * CAPC * CDIM * 2); // [E][CAP][768]
  __hip_bfloat16* hbuf = (__hip_bfloat16*)take((size_t)E_EXP * CAPC * HDIM * 2); // [E][CAP][3072]
  __hip_bfloat16* eout = (__hip_bfloat16*)take((size_t)E_EXP * CAPC * CDIM * 2); // [E][CAP][768] bf16
  int*   eidx = (int*)take((size_t)2 * N_TOK * 4);
  float* pv   = (float*)take((size_t)2 * N_TOK * 4);
  int*   slot = (int*)take((size_t)2 * N_TOK * 4);
  int*   stok = (int*)take((size_t)E_EXP * CAPC * 4);
  int*   ecnt = (int*)take((size_t)E_EXP * 4);
  int*   work2 = (int*)take((size_t)128 * 4);
  int*   wcnt = (int*)take((size_t)2 * 4);

  hipFuncSetAttribute((const void*)gemm1p,
                      hipFuncAttributeMaxDynamicSharedMemorySize, 65536);
  hipFuncSetAttribute((const void*)gemm2x,
                      hipFuncAttributeMaxDynamicSharedMemorySize, 65536);

  // fused prep: LDS-free tiled weight transposes (non-temporal reads) + router
  prep_kernel<<<4608 + 1024, 256, 0, stream>>>(cfc, cpr, wfcT, wprT, x, wg, eidx, pv);
  scan_kernel<<<1, 256, 0, stream>>>(eidx, slot, stok, ecnt, work2, wcnt);
  dispatch_kernel<<<(E_EXP * CAPC) / 4, 256, 0, stream>>>(x, stok, ecnt, xin);

  // GEMM1 + bias + GELU -> h (bf16): persistent 512 blocks (2/CU), work-looped.
  gemm1p<<<512, 256, 65536, stream>>>(xin, wfcT, fcb, hbuf, work2, wcnt);
  // GEMM2 + bias -> eout (bf16): single round, <=768 active blocks.
  gemm2x<<<768, 256, 65536, stream>>>(hbuf, wprT, prb, eout, work2, wcnt);

  combine_kernel<<<N_TOK / 4, 256, 0, stream>>>(eout, eidx, pv, slot, out);
}

// Round 19
// 168.710 us; speedup vs baseline: 1.0670x; 1.0140x over previous
//
#include <hip/hip_runtime.h>
#include <hip/hip_bf16.h>
#include <math.h>

// Problem constants (B=4, T=1024, C=768, E=8, K=2)
#define N_TOK 4096
#define CDIM  768
#define E_EXP 8
#define CAPC  2048
#define HDIM  3072   // 4*C

typedef __attribute__((ext_vector_type(8))) short short8;
typedef __attribute__((ext_vector_type(4))) float floatx4;

#define VMCNT(n) asm volatile("s_waitcnt vmcnt(" #n ")" ::: "memory")
#define LGKM(n)  asm volatile("s_waitcnt lgkmcnt(" #n ")" ::: "memory")
#define SB0()    __builtin_amdgcn_sched_barrier(0)

static __device__ __forceinline__ unsigned short f2bf(float f) {
  __hip_bfloat16 h = __float2bfloat16(f);
  return __builtin_bit_cast(unsigned short, h);
}
static __device__ __forceinline__ float bf2f(unsigned short u) {
  return __builtin_bit_cast(float, (unsigned int)u << 16);
}

// ---------------------------------------------------------------------------
// K1: fused prep — LDS-free weight transpose into tiled bf16 layout + router.
// Non-temporal weight reads (proven r18: streams from HBM instead of the
// ~2.1TB/s L3-serve path).  Tiled layout: W^T as [e][bx][kt][128 n][64 k]
// 16KB tiles; GEMM stage_b reads tile_base + kt*16384 + li*128 + kb.
// blockIdx partition: [0,2304) c_fc; [2304,4608) c_proj; [4608,5632) router.
// ---------------------------------------------------------------------------
__global__ __launch_bounds__(256)
void prep_kernel(const float* __restrict__ cfc, const float* __restrict__ cpr,
                 __hip_bfloat16* __restrict__ wfcT, __hip_bfloat16* __restrict__ wprT,
                 const float* __restrict__ x, const float* __restrict__ wg,
                 int* __restrict__ eidx, float* __restrict__ pval)
{
  const int b = blockIdx.x;
  const int t = threadIdx.x;
  if (b < 4608) {
    const float* src;
    unsigned short* dstT;
    int Cc;
    if (b < 2304) {
      // c_fc [E][768][3072]: e<8, kt<12, bx<24
      const int e = b / 288, rem = b % 288;
      const int kt = rem / 24, bx = rem % 24;
      src = cfc + (size_t)e * CDIM * HDIM + (size_t)(kt * 64) * HDIM + bx * 128;
      Cc = HDIM;
      dstT = (unsigned short*)wfcT + (((size_t)e * 24 + bx) * 12 + kt) * 8192;
    } else {
      // c_proj [E][3072][768]: e<8, kt<48, bx<6
      const int bb = b - 2304;
      const int e = bb / 288, rem = bb % 288;
      const int kt = rem / 6, bx = rem % 6;
      src = cpr + (size_t)e * HDIM * CDIM + (size_t)(kt * 64) * CDIM + bx * 128;
      Cc = CDIM;
      dstT = (unsigned short*)wprT + (((size_t)e * 6 + bx) * 48 + kt) * 8192;
    }
    const int nq = t & 31, ko = t >> 5;          // column-quad, k-octet
    const float* colp = src + (size_t)(ko * 8) * Cc + nq * 4;
    unsigned short obuf[4][8];                   // [c][j], static indexing
#pragma unroll
    for (int j = 0; j < 8; ++j) {
      const floatx4 v = __builtin_nontemporal_load((const floatx4*)(colp + (size_t)j * Cc));
      obuf[0][j] = f2bf(v[0]); obuf[1][j] = f2bf(v[1]);
      obuf[2][j] = f2bf(v[2]); obuf[3][j] = f2bf(v[3]);
    }
#pragma unroll
    for (int c = 0; c < 4; ++c)
      *(short8*)(dstT + (size_t)(nq * 4 + c) * 64 + ko * 8) = *(short8*)&obuf[c][0];
  } else {
    // router: one wave per token
    const int wv = t >> 6, lane = t & 63;
    const int n = (b - 4608) * 4 + wv;
    const float* xr = x + (size_t)n * CDIM;
    float acc[E_EXP] = {0.f, 0.f, 0.f, 0.f, 0.f, 0.f, 0.f, 0.f};
#pragma unroll
    for (int i = 0; i < CDIM / 64; ++i) {
      const float xv = xr[i * 64 + lane];
#pragma unroll
      for (int e = 0; e < E_EXP; ++e)
        acc[e] = fmaf(xv, wg[e * CDIM + i * 64 + lane], acc[e]);
    }
#pragma unroll
    for (int e = 0; e < E_EXP; ++e) {
#pragma unroll
      for (int off = 32; off > 0; off >>= 1)
        acc[e] += __shfl_xor(acc[e], off);
    }
    if (lane == 0) {
      int e0 = 0; float v0 = acc[0];
#pragma unroll
      for (int e = 1; e < E_EXP; ++e) if (acc[e] > v0) { v0 = acc[e]; e0 = e; }
      int e1 = -1; float v1 = -3.4e38f;
#pragma unroll
      for (int e = 0; e < E_EXP; ++e) if (e != e0 && acc[e] > v1) { v1 = acc[e]; e1 = e; }
      const float ex = __expf(v1 - v0);
      const float inv = 1.f / (1.f + ex);
      eidx[n] = e0; eidx[N_TOK + n] = e1;
      pval[n] = inv; pval[N_TOK + n] = ex * inv;
    }
  }
}

// ---------------------------------------------------------------------------
// K4: capacity scan (k-major reference order), single block Hillis-Steele.
// Emits ecnt[e] and a compact 128-row-tile work list shared by both GEMMs.
// ---------------------------------------------------------------------------
__global__ __launch_bounds__(256)
void scan_kernel(const int* __restrict__ eidx, int* __restrict__ slot,
                 int* __restrict__ slot_token, int* __restrict__ ecnt,
                 int* __restrict__ work2, int* __restrict__ wcnt)
{
  const int t = threadIdx.x;
  const int base = t * 32;
  int e_local[32];
  int cnt[E_EXP] = {0, 0, 0, 0, 0, 0, 0, 0};
#pragma unroll
  for (int i = 0; i < 32; ++i) {
    const int e = eidx[base + i];
    e_local[i] = e;
    cnt[e]++;
  }
  __shared__ int hist[256][E_EXP];
  __shared__ int secnt[E_EXP];
#pragma unroll
  for (int e = 0; e < E_EXP; ++e) hist[t][e] = cnt[e];
  __syncthreads();
  for (int off = 1; off < 256; off <<= 1) {
    int v[E_EXP] = {0, 0, 0, 0, 0, 0, 0, 0};
    if (t >= off) {
#pragma unroll
      for (int e = 0; e < E_EXP; ++e) v[e] = hist[t - off][e];
    }
    __syncthreads();
    if (t >= off) {
#pragma unroll
      for (int e = 0; e < E_EXP; ++e) hist[t][e] += v[e];
    }
    __syncthreads();
  }
  if (t == 255) {
#pragma unroll
    for (int e = 0; e < E_EXP; ++e) {
      const int tot = hist[255][e];
      const int c = tot < CAPC ? tot : CAPC;
      ecnt[e] = c;
      secnt[e] = c;
    }
  }
  __syncthreads();
  if (t == 0) {
    int n2 = 0;
    for (int e = 0; e < E_EXP; ++e) {
      const int c = secnt[e];
      const int t2 = (c + 127) >> 7;
      for (int b = 0; b < t2; ++b) work2[n2++] = (e << 8) | b;
    }
    wcnt[0] = n2 * 24;
    wcnt[1] = n2 * 6;
  }
  int run[E_EXP];
#pragma unroll
  for (int e = 0; e < E_EXP; ++e) run[e] = hist[t][e] - cnt[e];
#pragma unroll
  for (int i = 0; i < 32; ++i) {
    const int a = base + i;
    const int e = e_local[i];
    const int r = run[e]++;
    const int s = (r < CAPC) ? r : -1;
    slot[a] = s;
    if (s >= 0) slot_token[e * CAPC + s] = (a < N_TOK) ? a : (a - N_TOK);
  }
}

// ---------------------------------------------------------------------------
// K5: dispatch — exp_in row = bf16(x[token]) for used slots only.
// ---------------------------------------------------------------------------
__global__ __launch_bounds__(256)
void dispatch_kernel(const float* __restrict__ x, const int* __restrict__ slot_token,
                     const int* __restrict__ ecnt, __hip_bfloat16* __restrict__ xin)
{
  const int wv = threadIdx.x >> 6, lane = threadIdx.x & 63;
  const int s = blockIdx.x * 4 + wv;
  const int e = s >> 11;                 // CAPC = 2048
  if ((s & (CAPC - 1)) >= ecnt[e]) return;
  const int n = slot_token[s];
  unsigned short* orow = (unsigned short*)xin + (size_t)s * CDIM;
  const float4* xr = (const float4*)(x + (size_t)n * CDIM);
#pragma unroll
  for (int i = 0; i < 3; ++i) {
    const float4 v = xr[i * 64 + lane];
    ushort4 o;
    o.x = f2bf(v.x); o.y = f2bf(v.y); o.z = f2bf(v.z); o.w = f2bf(v.w);
    *(ushort4*)(orow + (size_t)(i * 64 + lane) * 4) = o;
  }
}

// ---------------------------------------------------------------------------
// K6 core: 128x128-tile GEMM body, BK=64, 4 waves (2Mx2N), dbuf 64 KiB,
// counted vmcnt + counted LGKM (proven round-5..18 body).
// A: row-major [slot][K]; B: tiled [bx][kt][128][64] (16KB tiles).
// ---------------------------------------------------------------------------
__device__ __forceinline__ void stage_a(const __hip_bfloat16* Ae, char* lds,
                                        int K, int kt, int wv, int lane)
{
  char* dst = lds + (kt & 1) * 32768;
#pragma unroll
  for (int j = 0; j < 4; ++j) {
    const int li = j * 32 + wv * 8 + (lane >> 3);
    const int kb = ((lane & 7) * 16) ^ ((li & 7) << 4);
    const char* g = (const char*)Ae + ((size_t)li * K + (size_t)kt * 64) * 2 + kb;
    __builtin_amdgcn_global_load_lds((const __attribute__((address_space(1))) unsigned int*)g,
                                     (__attribute__((address_space(3))) unsigned int*)(dst + j * 4096 + wv * 1024),
                                     16, 0, 0);
  }
}
__device__ __forceinline__ void stage_b(const char* BeT, char* lds,
                                        int kt, int wv, int lane)
{
  char* dst = lds + (kt & 1) * 32768 + 16384;
#pragma unroll
  for (int j = 0; j < 4; ++j) {
    const int li = j * 32 + wv * 8 + (lane >> 3);
    const int kb = ((lane & 7) * 16) ^ ((li & 7) << 4);
    const char* g = BeT + (size_t)kt * 16384 + li * 128 + kb;
    __builtin_amdgcn_global_load_lds((const __attribute__((address_space(1))) unsigned int*)g,
                                     (__attribute__((address_space(3))) unsigned int*)(dst + j * 4096 + wv * 1024),
                                     16, 0, 0);
  }
}

template<int VME, bool S2>
__device__ __forceinline__ void ktile2(int kt, char* lds,
                                       const __hip_bfloat16* Ae, const char* BeT,
                                       int K, floatx4 (&acc)[4][4],
                                       int wm, int wn, int fr, int fk, int wv, int lane)
{
  if constexpr (VME == 8) VMCNT(8); else VMCNT(0);
  __builtin_amdgcn_s_barrier();
  SB0();
  const char* bufA = lds + ((kt & 1) ? 32768 : 0);
  const char* bufB = bufA + 16384;
  short8 a[4][2], b[4][2];
#pragma unroll
  for (int mi = 0; mi < 4; ++mi) {
    const int lr = wm * 64 + mi * 16 + fr;
    a[mi][0] = *(const short8*)(bufA + lr * 128 + ((fk * 16) ^ ((lr & 7) << 4)));
  }
#pragma unroll
  for (int ni = 0; ni < 4; ++ni) {
    const int lj = wn * 64 + ni * 16 + fr;
    b[ni][0] = *(const short8*)(bufB + lj * 128 + ((fk * 16) ^ ((lj & 7) << 4)));
  }
  SB0();
#pragma unroll
  for (int mi = 0; mi < 4; ++mi) {
    const int lr = wm * 64 + mi * 16 + fr;
    a[mi][1] = *(const short8*)(bufA + lr * 128 + ((64 + fk * 16) ^ ((lr & 7) << 4)));
  }
#pragma unroll
  for (int ni = 0; ni < 4; ++ni) {
    const int lj = wn * 64 + ni * 16 + fr;
    b[ni][1] = *(const short8*)(bufB + lj * 128 + ((64 + fk * 16) ^ ((lj & 7) << 4)));
  }
  SB0();
  LGKM(8); SB0();
  __builtin_amdgcn_s_setprio(1);
#pragma unroll
  for (int mi = 0; mi < 4; ++mi)
#pragma unroll
    for (int ni = 0; ni < 4; ++ni)
      acc[mi][ni] = __builtin_amdgcn_mfma_f32_16x16x32_bf16(a[mi][0], b[ni][0], acc[mi][ni], 0, 0, 0);
  __builtin_amdgcn_s_setprio(0);
  SB0();
  LGKM(0); SB0();
  __builtin_amdgcn_s_setprio(1);
#pragma unroll
  for (int mi = 0; mi < 4; ++mi)
#pragma unroll
    for (int ni = 0; ni < 4; ++ni)
      acc[mi][ni] = __builtin_amdgcn_mfma_f32_16x16x32_bf16(a[mi][1], b[ni][1], acc[mi][ni], 0, 0, 0);
  __builtin_amdgcn_s_setprio(0);
  SB0();
  __builtin_amdgcn_s_barrier();
  if (S2) {
    stage_a(Ae, lds, K, kt + 2, wv, lane);
    stage_b(BeT, lds, kt + 2, wv, lane);
  }
  SB0();
}

// fast exact-grade GELU: tanh form, |err| ~3e-4 << bf16 rounding of the output
static __device__ __forceinline__ float gelu_fast(float v) {
  const float u2 = v * (1.5957691216f + 0.0713548163f * v * v);
  const float ez = __expf(u2);
  return v * ez / (ez + 1.0f);
}

// Shared epilogue: LDS-staged coalesced bf16 store (wave-private 2KB region).
template<int EPI>
__device__ __forceinline__ void epilogue_bf16(floatx4 (&acc)[4][4], char* lds,
                                              const float* be, unsigned short* Cb,
                                              int Nn, int m0, int n0,
                                              int wm, int wn, int fr, int fk,
                                              int wv, int lane)
{
  unsigned short* ep = (unsigned short*)(lds + wv * 2048);
  float bcol[4];
#pragma unroll
  for (int ni = 0; ni < 4; ++ni) bcol[ni] = be[n0 + wn * 64 + ni * 16 + fr];
#pragma unroll
  for (int mi = 0; mi < 4; ++mi) {
#pragma unroll
    for (int ni = 0; ni < 4; ++ni)
#pragma unroll
      for (int j = 0; j < 4; ++j) {
        float v = acc[mi][ni][j] + bcol[ni];
        if (EPI == 1) v = gelu_fast(v);
        const int row = fk * 4 + j;
        *(unsigned short*)((char*)ep + row * 128 + ((ni * 32 + fr * 2) ^ (fk << 5))) = f2bf(v);
      }
    LGKM(0); SB0();
    const int r = lane & 15;
    const int grow = m0 + wm * 64 + mi * 16 + r;
#pragma unroll
    for (int it = 0; it < 2; ++it) {
      const int q = (lane >> 4) + it * 4;
      const short8 vv = *(const short8*)((char*)ep + r * 128 + ((q * 16) ^ ((r >> 2) << 5)));
      *(short8*)(Cb + (size_t)grow * Nn + n0 + wn * 64 + q * 8) = vv;
    }
    LGKM(0); SB0();
  }
}

// ---------------------------------------------------------------------------
// K6a: GEMM1 persistent — grid 512 (2 blocks/CU); balanced PAIR split per XCD
// + BX-MAJOR item order: concurrent slots cover ~8 bx x ~8 pairs ->
// B working set ~1.5MB + A ~1.6MB, both XCD-L2-resident (was 4.6MB B,
// L2-thrash -> FETCH 94MB, L3-latency staging stalls).
// B tiled: [e][bx<24][kt<12][128][64].
// ---------------------------------------------------------------------------
__global__ __launch_bounds__(256, 2)
void gemm1p(const __hip_bfloat16* __restrict__ A, const __hip_bfloat16* __restrict__ Bt,
            const float* __restrict__ bias, __hip_bfloat16* __restrict__ Cout,
            const int* __restrict__ work, const int* __restrict__ wcnt)
{
  extern __shared__ __align__(16) char lds[];
  const int P = wcnt[0] / 24;                 // total pairs
  const int x8 = blockIdx.x & 7, l = blockIdx.x >> 3;
  const int p0 = (x8 * P) >> 3;               // balanced pair split per XCD
  const int p1 = ((x8 + 1) * P) >> 3;
  const int px = p1 - p0;                     // pairs on this XCD (>=2 always)
  const int items_x = px * 24;

  const int t = threadIdx.x, wv = t >> 6, lane = t & 63;
  const int wm = wv >> 1, wn = wv & 1;
  const int fr = lane & 15, fk = lane >> 4;
  constexpr int ntk = CDIM / 64;   // 12

  for (int il = l; il < items_x; il += 64) {
    const int bx = il / px;                   // bx-major ordering
    const int p  = p0 + (il - bx * px);
    const int w = work[p];
    const int e = w >> 8, by = w & 255;

    const __hip_bfloat16* Ae = A + (size_t)e * CAPC * CDIM + (size_t)by * 128 * CDIM;
    const char* BeT = (const char*)Bt + (((size_t)e * 24 + bx) * 12) * 16384;

    floatx4 acc[4][4] = {};

    stage_a(Ae, lds, CDIM, 0, wv, lane);
    stage_b(BeT, lds, 0, wv, lane);
    stage_a(Ae, lds, CDIM, 1, wv, lane);
    stage_b(BeT, lds, 1, wv, lane);
    SB0();

#pragma unroll 1
    for (int kt = 0; kt < ntk - 2; ++kt)
      ktile2<8, true>(kt, lds, Ae, BeT, CDIM, acc, wm, wn, fr, fk, wv, lane);
    ktile2<8, false>(ntk - 2, lds, Ae, BeT, CDIM, acc, wm, wn, fr, fk, wv, lane);
    ktile2<0, false>(ntk - 1, lds, Ae, BeT, CDIM, acc, wm, wn, fr, fk, wv, lane);

    epilogue_bf16<1>(acc, lds,
                     bias + (size_t)e * HDIM,
                     (unsigned short*)Cout + (size_t)e * CAPC * HDIM,
                     HDIM, by * 128, bx * 128, wm, wn, fr, fk, wv, lane);
    __builtin_amdgcn_s_barrier();   // all waves done with LDS epilogue regions
    SB0();
  }
}

// ---------------------------------------------------------------------------
// K6b: GEMM2 — single round; B tiled: [e][bx<6][kt<48][128][64].
// ---------------------------------------------------------------------------
__global__ __launch_bounds__(256, 2)
void gemm2x(const __hip_bfloat16* __restrict__ A, const __hip_bfloat16* __restrict__ Bt,
            const float* __restrict__ bias, __hip_bfloat16* __restrict__ Cout,
            const int* __restrict__ work, const int* __restrict__ wcnt)
{
  extern __shared__ __align__(16) char lds[];
  const int T = wcnt[1];
  const int bId = blockIdx.x;
  const int cpx = (T + 7) >> 3;
  if ((bId >> 3) >= cpx) return;
  const int idx = (bId & 7) * cpx + (bId >> 3);
  if (idx >= T) return;
  const int p = idx / 6;
  const int bx0 = idx % 6;
  const int bx = (p & 1) ? (5 - bx0) : bx0;
  const int w = work[p];
  const int e = w >> 8, by = w & 255;

  const int t = threadIdx.x, wv = t >> 6, lane = t & 63;
  const int wm = wv >> 1, wn = wv & 1;
  const int fr = lane & 15, fk = lane >> 4;
  constexpr int ntk = HDIM / 64;   // 48

  const __hip_bfloat16* Ae = A + (size_t)e * CAPC * HDIM + (size_t)by * 128 * HDIM;
  const char* BeT = (const char*)Bt + (((size_t)e * 6 + bx) * 48) * 16384;

  floatx4 acc[4][4] = {};

  stage_a(Ae, lds, HDIM, 0, wv, lane);
  stage_b(BeT, lds, 0, wv, lane);
  stage_a(Ae, lds, HDIM, 1, wv, lane);
  stage_b(BeT, lds, 1, wv, lane);
  SB0();

#pragma unroll 1
  for (int kt = 0; kt < ntk - 2; ++kt)
    ktile2<8, true>(kt, lds, Ae, BeT, HDIM, acc, wm, wn, fr, fk, wv, lane);
  ktile2<8, false>(ntk - 2, lds, Ae, BeT, HDIM, acc, wm, wn, fr, fk, wv, lane);
  ktile2<0, false>(ntk - 1, lds, Ae, BeT, HDIM, acc, wm, wn, fr, fk, wv, lane);

  epilogue_bf16<2>(acc, lds,
                   bias + (size_t)e * CDIM,
                   (unsigned short*)Cout + (size_t)e * CAPC * CDIM,
                   CDIM, by * 128, bx * 128, wm, wn, fr, fk, wv, lane);
}

// ---------------------------------------------------------------------------
// K7: combine — out[n] = w0*exp_out[e0][s0] + w1*exp_out[e1][s1], bf16 eout.
// ---------------------------------------------------------------------------
__global__ __launch_bounds__(256)
void combine_kernel(const __hip_bfloat16* __restrict__ eout, const int* __restrict__ eidx,
                    const float* __restrict__ pval, const int* __restrict__ slot,
                    float* __restrict__ out)
{
  const int wv = threadIdx.x >> 6, lane = threadIdx.x & 63;
  const int n = blockIdx.x * 4 + wv;
  const int e0 = eidx[n], e1 = eidx[N_TOK + n];
  int s0 = slot[n], s1 = slot[N_TOK + n];
  const float w0 = (s0 >= 0) ? pval[n] : 0.f;
  const float w1 = (s1 >= 0) ? pval[N_TOK + n] : 0.f;
  s0 = (s0 >= 0) ? s0 : 0;
  s1 = (s1 >= 0) ? s1 : 0;
  const ushort4* r0 = (const ushort4*)((const unsigned short*)eout + ((size_t)e0 * CAPC + s0) * CDIM);
  const ushort4* r1 = (const ushort4*)((const unsigned short*)eout + ((size_t)e1 * CAPC + s1) * CDIM);
  float4* o = (float4*)(out + (size_t)n * CDIM);
#pragma unroll
  for (int i = 0; i < 3; ++i) {
    const ushort4 a = r0[i * 64 + lane];
    const ushort4 b = r1[i * 64 + lane];
    float4 c;
    c.x = w0 * bf2f(a.x) + w1 * bf2f(b.x);
    c.y = w0 * bf2f(a.y) + w1 * bf2f(b.y);
    c.z = w0 * bf2f(a.z) + w1 * bf2f(b.z);
    c.w = w0 * bf2f(a.w) + w1 * bf2f(b.w);
    o[i * 64 + lane] = c;
  }
}

// ---------------------------------------------------------------------------
extern "C" void kernel_launch(void* const* d_in, const int* in_sizes, int n_in,
                              void* d_out, int out_size, void* d_ws, size_t ws_size,
                              hipStream_t stream)
{
  const float* x   = (const float*)d_in[0];
  const float* wg  = (const float*)d_in[1];
  const float* cfc = (const float*)d_in[2];
  const float* fcb = (const float*)d_in[3];
  const float* cpr = (const float*)d_in[4];
  const float* prb = (const float*)d_in[5];
  float* out = (float*)d_out;

  char* ws = (char*)d_ws;
  size_t off = 0;
  auto take = [&](size_t bytes) -> void* {
    void* p = ws + off;
    off += (bytes + 255) & ~(size_t)255;
    return p;
  };
  __hip_bfloat16* wfcT = (__hip_bfloat16*)take((size_t)E_EXP * HDIM * CDIM * 2); // tiled [e][24][12][128][64]
  __hip_bfloat16* wprT = (__hip_bfloat16*)take((size_t)E_EXP * CDIM * HDIM * 2); // tiled [e][6][48][128][64]
  __hip_bfloat16* xin  = (__hip_bfloat16*)take((size_t)E_EXP * CAPC * CDIM * 2); // [E][CAP][768]
  __hip_bfloat16* hbuf = (__hip_bfloat16*)take((size_t)E_EXP * CAPC * HDIM * 2); // [E][CAP][3072]
  __hip_bfloat16* eout = (__hip_bfloat16*)take((size_t)E_EXP * CAPC * CDIM * 2); // [E][CAP][768] bf16
  int*   eidx = (int*)take((size_t)2 * N_TOK * 4);
  float* pv   = (float*)take((size_t)2 * N_TOK * 4);
  int*   slot = (int*)take((size_t)2 * N_TOK * 4);
  int*   stok = (int*)take((size_t)E_EXP * CAPC * 4);
  int*   ecnt = (int*)take((size_t)E_EXP * 4);
  int*   work2 = (int*)take((size_t)128 * 4);
  int*   wcnt = (int*)take((size_t)2 * 4);

  hipFuncSetAttribute((const void*)gemm1p,
                      hipFuncAttributeMaxDynamicSharedMemorySize, 65536);
  hipFuncSetAttribute((const void*)gemm2x,
                      hipFuncAttributeMaxDynamicSharedMemorySize, 65536);

  // fused prep: LDS-free tiled weight transposes (non-temporal reads) + router
  prep_kernel<<<4608 + 1024, 256, 0, stream>>>(cfc, cpr, wfcT, wprT, x, wg, eidx, pv);
  scan_kernel<<<1, 256, 0, stream>>>(eidx, slot, stok, ecnt, work2, wcnt);
  dispatch_kernel<<<(E_EXP * CAPC) / 4, 256, 0, stream>>>(x, stok, ecnt, xin);

  // GEMM1 + bias + GELU -> h (bf16): persistent 512 blocks, bx-major order.
  gemm1p<<<512, 256, 65536, stream>>>(xin, wfcT, fcb, hbuf, work2, wcnt);
  // GEMM2 + bias -> eout (bf16): single round, <=768 active blocks.
  gemm2x<<<768, 256, 65536, stream>>>(hbuf, wprT, prb, eout, work2, wcnt);

  combine_kernel<<<N_TOK / 4, 256, 0, stream>>>(eout, eidx, pv, slot, out);
}

// Round 20
// 165.992 us; speedup vs baseline: 1.0845x; 1.0164x over previous
//
#include <hip/hip_runtime.h>
#include <hip/hip_bf16.h>
#include <math.h>

// Problem constants (B=4, T=1024, C=768, E=8, K=2)
#define N_TOK 4096
#define CDIM  768
#define E_EXP 8
#define CAPC  2048
#define HDIM  3072   // 4*C

typedef __attribute__((ext_vector_type(8))) short short8;
typedef __attribute__((ext_vector_type(4))) float floatx4;

#define VMCNT(n) asm volatile("s_waitcnt vmcnt(" #n ")" ::: "memory")
#define LGKM(n)  asm volatile("s_waitcnt lgkmcnt(" #n ")" ::: "memory")
#define SB0()    __builtin_amdgcn_sched_barrier(0)

static __device__ __forceinline__ unsigned short f2bf(float f) {
  __hip_bfloat16 h = __float2bfloat16(f);
  return __builtin_bit_cast(unsigned short, h);
}
static __device__ __forceinline__ float bf2f(unsigned short u) {
  return __builtin_bit_cast(float, (unsigned int)u << 16);
}

// ---------------------------------------------------------------------------
// K1: fused prep — LDS-free weight transpose into tiled bf16 layout + router.
// Non-temporal weight reads (proven r18).  Tiled layout: W^T as
// [e][bx][kt][128 n][64 k] 16KB tiles.
// blockIdx partition: [0,2304) c_fc; [2304,4608) c_proj; [4608,5632) router.
// ---------------------------------------------------------------------------
__global__ __launch_bounds__(256)
void prep_kernel(const float* __restrict__ cfc, const float* __restrict__ cpr,
                 __hip_bfloat16* __restrict__ wfcT, __hip_bfloat16* __restrict__ wprT,
                 const float* __restrict__ x, const float* __restrict__ wg,
                 int* __restrict__ eidx, float* __restrict__ pval)
{
  const int b = blockIdx.x;
  const int t = threadIdx.x;
  if (b < 4608) {
    const float* src;
    unsigned short* dstT;
    int Cc;
    if (b < 2304) {
      const int e = b / 288, rem = b % 288;
      const int kt = rem / 24, bx = rem % 24;
      src = cfc + (size_t)e * CDIM * HDIM + (size_t)(kt * 64) * HDIM + bx * 128;
      Cc = HDIM;
      dstT = (unsigned short*)wfcT + (((size_t)e * 24 + bx) * 12 + kt) * 8192;
    } else {
      const int bb = b - 2304;
      const int e = bb / 288, rem = bb % 288;
      const int kt = rem / 6, bx = rem % 6;
      src = cpr + (size_t)e * HDIM * CDIM + (size_t)(kt * 64) * CDIM + bx * 128;
      Cc = CDIM;
      dstT = (unsigned short*)wprT + (((size_t)e * 6 + bx) * 48 + kt) * 8192;
    }
    const int nq = t & 31, ko = t >> 5;
    const float* colp = src + (size_t)(ko * 8) * Cc + nq * 4;
    unsigned short obuf[4][8];
#pragma unroll
    for (int j = 0; j < 8; ++j) {
      const floatx4 v = __builtin_nontemporal_load((const floatx4*)(colp + (size_t)j * Cc));
      obuf[0][j] = f2bf(v[0]); obuf[1][j] = f2bf(v[1]);
      obuf[2][j] = f2bf(v[2]); obuf[3][j] = f2bf(v[3]);
    }
#pragma unroll
    for (int c = 0; c < 4; ++c)
      *(short8*)(dstT + (size_t)(nq * 4 + c) * 64 + ko * 8) = *(short8*)&obuf[c][0];
  } else {
    const int wv = t >> 6, lane = t & 63;
    const int n = (b - 4608) * 4 + wv;
    const float* xr = x + (size_t)n * CDIM;
    float acc[E_EXP] = {0.f, 0.f, 0.f, 0.f, 0.f, 0.f, 0.f, 0.f};
#pragma unroll
    for (int i = 0; i < CDIM / 64; ++i) {
      const float xv = xr[i * 64 + lane];
#pragma unroll
      for (int e = 0; e < E_EXP; ++e)
        acc[e] = fmaf(xv, wg[e * CDIM + i * 64 + lane], acc[e]);
    }
#pragma unroll
    for (int e = 0; e < E_EXP; ++e) {
#pragma unroll
      for (int off = 32; off > 0; off >>= 1)
        acc[e] += __shfl_xor(acc[e], off);
    }
    if (lane == 0) {
      int e0 = 0; float v0 = acc[0];
#pragma unroll
      for (int e = 1; e < E_EXP; ++e) if (acc[e] > v0) { v0 = acc[e]; e0 = e; }
      int e1 = -1; float v1 = -3.4e38f;
#pragma unroll
      for (int e = 0; e < E_EXP; ++e) if (e != e0 && acc[e] > v1) { v1 = acc[e]; e1 = e; }
      const float ex = __expf(v1 - v0);
      const float inv = 1.f / (1.f + ex);
      eidx[n] = e0; eidx[N_TOK + n] = e1;
      pval[n] = inv; pval[N_TOK + n] = ex * inv;
    }
  }
}

// ---------------------------------------------------------------------------
// K4: capacity scan (k-major reference order), single block Hillis-Steele.
// ---------------------------------------------------------------------------
__global__ __launch_bounds__(256)
void scan_kernel(const int* __restrict__ eidx, int* __restrict__ slot,
                 int* __restrict__ slot_token, int* __restrict__ ecnt,
                 int* __restrict__ work2, int* __restrict__ wcnt)
{
  const int t = threadIdx.x;
  const int base = t * 32;
  int e_local[32];
  int cnt[E_EXP] = {0, 0, 0, 0, 0, 0, 0, 0};
#pragma unroll
  for (int i = 0; i < 32; ++i) {
    const int e = eidx[base + i];
    e_local[i] = e;
    cnt[e]++;
  }
  __shared__ int hist[256][E_EXP];
  __shared__ int secnt[E_EXP];
#pragma unroll
  for (int e = 0; e < E_EXP; ++e) hist[t][e] = cnt[e];
  __syncthreads();
  for (int off = 1; off < 256; off <<= 1) {
    int v[E_EXP] = {0, 0, 0, 0, 0, 0, 0, 0};
    if (t >= off) {
#pragma unroll
      for (int e = 0; e < E_EXP; ++e) v[e] = hist[t - off][e];
    }
    __syncthreads();
    if (t >= off) {
#pragma unroll
      for (int e = 0; e < E_EXP; ++e) hist[t][e] += v[e];
    }
    __syncthreads();
  }
  if (t == 255) {
#pragma unroll
    for (int e = 0; e < E_EXP; ++e) {
      const int tot = hist[255][e];
      const int c = tot < CAPC ? tot : CAPC;
      ecnt[e] = c;
      secnt[e] = c;
    }
  }
  __syncthreads();
  if (t == 0) {
    int n2 = 0;
    for (int e = 0; e < E_EXP; ++e) {
      const int c = secnt[e];
      const int t2 = (c + 127) >> 7;
      for (int b = 0; b < t2; ++b) work2[n2++] = (e << 8) | b;
    }
    wcnt[0] = n2 * 24;
    wcnt[1] = n2 * 6;
  }
  int run[E_EXP];
#pragma unroll
  for (int e = 0; e < E_EXP; ++e) run[e] = hist[t][e] - cnt[e];
#pragma unroll
  for (int i = 0; i < 32; ++i) {
    const int a = base + i;
    const int e = e_local[i];
    const int r = run[e]++;
    const int s = (r < CAPC) ? r : -1;
    slot[a] = s;
    if (s >= 0) slot_token[e * CAPC + s] = (a < N_TOK) ? a : (a - N_TOK);
  }
}

// ---------------------------------------------------------------------------
// K5: dispatch — exp_in row = bf16(x[token]) for used slots only.
// ---------------------------------------------------------------------------
__global__ __launch_bounds__(256)
void dispatch_kernel(const float* __restrict__ x, const int* __restrict__ slot_token,
                     const int* __restrict__ ecnt, __hip_bfloat16* __restrict__ xin)
{
  const int wv = threadIdx.x >> 6, lane = threadIdx.x & 63;
  const int s = blockIdx.x * 4 + wv;
  const int e = s >> 11;
  if ((s & (CAPC - 1)) >= ecnt[e]) return;
  const int n = slot_token[s];
  unsigned short* orow = (unsigned short*)xin + (size_t)s * CDIM;
  const float4* xr = (const float4*)(x + (size_t)n * CDIM);
#pragma unroll
  for (int i = 0; i < 3; ++i) {
    const float4 v = xr[i * 64 + lane];
    ushort4 o;
    o.x = f2bf(v.x); o.y = f2bf(v.y); o.z = f2bf(v.z); o.w = f2bf(v.w);
    *(ushort4*)(orow + (size_t)(i * 64 + lane) * 4) = o;
  }
}

// ---------------------------------------------------------------------------
// K6 core: 128x128-tile GEMM body (proven round-5..19).
// ---------------------------------------------------------------------------
__device__ __forceinline__ void stage_a(const __hip_bfloat16* Ae, char* lds,
                                        int K, int kt, int wv, int lane)
{
  char* dst = lds + (kt & 1) * 32768;
#pragma unroll
  for (int j = 0; j < 4; ++j) {
    const int li = j * 32 + wv * 8 + (lane >> 3);
    const int kb = ((lane & 7) * 16) ^ ((li & 7) << 4);
    const char* g = (const char*)Ae + ((size_t)li * K + (size_t)kt * 64) * 2 + kb;
    __builtin_amdgcn_global_load_lds((const __attribute__((address_space(1))) unsigned int*)g,
                                     (__attribute__((address_space(3))) unsigned int*)(dst + j * 4096 + wv * 1024),
                                     16, 0, 0);
  }
}
__device__ __forceinline__ void stage_b(const char* BeT, char* lds,
                                        int kt, int wv, int lane)
{
  char* dst = lds + (kt & 1) * 32768 + 16384;
#pragma unroll
  for (int j = 0; j < 4; ++j) {
    const int li = j * 32 + wv * 8 + (lane >> 3);
    const int kb = ((lane & 7) * 16) ^ ((li & 7) << 4);
    const char* g = BeT + (size_t)kt * 16384 + li * 128 + kb;
    __builtin_amdgcn_global_load_lds((const __attribute__((address_space(1))) unsigned int*)g,
                                     (__attribute__((address_space(3))) unsigned int*)(dst + j * 4096 + wv * 1024),
                                     16, 0, 0);
  }
}

template<int VME, bool S2>
__device__ __forceinline__ void ktile2(int kt, char* lds,
                                       const __hip_bfloat16* Ae, const char* BeT,
                                       int K, floatx4 (&acc)[4][4],
                                       int wm, int wn, int fr, int fk, int wv, int lane)
{
  if constexpr (VME == 8) VMCNT(8); else VMCNT(0);
  __builtin_amdgcn_s_barrier();
  SB0();
  const char* bufA = lds + ((kt & 1) ? 32768 : 0);
  const char* bufB = bufA + 16384;
  short8 a[4][2], b[4][2];
#pragma unroll
  for (int mi = 0; mi < 4; ++mi) {
    const int lr = wm * 64 + mi * 16 + fr;
    a[mi][0] = *(const short8*)(bufA + lr * 128 + ((fk * 16) ^ ((lr & 7) << 4)));
  }
#pragma unroll
  for (int ni = 0; ni < 4; ++ni) {
    const int lj = wn * 64 + ni * 16 + fr;
    b[ni][0] = *(const short8*)(bufB + lj * 128 + ((fk * 16) ^ ((lj & 7) << 4)));
  }
  SB0();
#pragma unroll
  for (int mi = 0; mi < 4; ++mi) {
    const int lr = wm * 64 + mi * 16 + fr;
    a[mi][1] = *(const short8*)(bufA + lr * 128 + ((64 + fk * 16) ^ ((lr & 7) << 4)));
  }
#pragma unroll
  for (int ni = 0; ni < 4; ++ni) {
    const int lj = wn * 64 + ni * 16 + fr;
    b[ni][1] = *(const short8*)(bufB + lj * 128 + ((64 + fk * 16) ^ ((lj & 7) << 4)));
  }
  SB0();
  LGKM(8); SB0();
  __builtin_amdgcn_s_setprio(1);
#pragma unroll
  for (int mi = 0; mi < 4; ++mi)
#pragma unroll
    for (int ni = 0; ni < 4; ++ni)
      acc[mi][ni] = __builtin_amdgcn_mfma_f32_16x16x32_bf16(a[mi][0], b[ni][0], acc[mi][ni], 0, 0, 0);
  __builtin_amdgcn_s_setprio(0);
  SB0();
  LGKM(0); SB0();
  __builtin_amdgcn_s_setprio(1);
#pragma unroll
  for (int mi = 0; mi < 4; ++mi)
#pragma unroll
    for (int ni = 0; ni < 4; ++ni)
      acc[mi][ni] = __builtin_amdgcn_mfma_f32_16x16x32_bf16(a[mi][1], b[ni][1], acc[mi][ni], 0, 0, 0);
  __builtin_amdgcn_s_setprio(0);
  SB0();
  __builtin_amdgcn_s_barrier();
  if (S2) {
    stage_a(Ae, lds, K, kt + 2, wv, lane);
    stage_b(BeT, lds, kt + 2, wv, lane);
  }
  SB0();
}

// cheap exact-grade GELU: exp2-folded tanh form + HW rcp (saves the exact-div
// sequence and the expf log2e mul).  |err| ~3e-4 << bf16 output rounding.
static __device__ __forceinline__ float gelu_fast(float v) {
  const float u2 = v * (2.3022184f + 0.1029434f * v * v);
  const float ez = exp2f(u2);
  return v * ez * __builtin_amdgcn_rcpf(ez + 1.0f);
}

// Shared epilogue: LDS-staged coalesced bf16 store; region base epb.
template<int EPI>
__device__ __forceinline__ void epilogue_bf16(floatx4 (&acc)[4][4], char* epb,
                                              const float* be, unsigned short* Cb,
                                              int Nn, int m0, int n0,
                                              int wm, int wn, int fr, int fk,
                                              int wv, int lane)
{
  unsigned short* ep = (unsigned short*)(epb + wv * 2048);
  float bcol[4];
#pragma unroll
  for (int ni = 0; ni < 4; ++ni) bcol[ni] = be[n0 + wn * 64 + ni * 16 + fr];
#pragma unroll
  for (int mi = 0; mi < 4; ++mi) {
#pragma unroll
    for (int ni = 0; ni < 4; ++ni)
#pragma unroll
      for (int j = 0; j < 4; ++j) {
        float v = acc[mi][ni][j] + bcol[ni];
        if (EPI == 1) v = gelu_fast(v);
        const int row = fk * 4 + j;
        *(unsigned short*)((char*)ep + row * 128 + ((ni * 32 + fr * 2) ^ (fk << 5))) = f2bf(v);
      }
    LGKM(0); SB0();
    const int r = lane & 15;
    const int grow = m0 + wm * 64 + mi * 16 + r;
#pragma unroll
    for (int it = 0; it < 2; ++it) {
      const int q = (lane >> 4) + it * 4;
      const short8 vv = *(const short8*)((char*)ep + r * 128 + ((q * 16) ^ ((r >> 2) << 5)));
      *(short8*)(Cb + (size_t)grow * Nn + n0 + wn * 64 + q * 8) = vv;
    }
    LGKM(0); SB0();
  }
}

// ---------------------------------------------------------------------------
// K6a: GEMM1 persistent — grid 512 (2/CU), balanced pair split + bx-major
// (r19).  NEW: next item's first two K-tiles staged BEFORE the epilogue
// (HBM/L2 latency hides under the epilogue VALU burst); epilogue uses a
// dedicated 8KB LDS region at 64KB (block LDS 72KB -> still 2 blocks/CU).
// Entry VMCNT(8) also counts younger epilogue stores: conservative-correct.
// ---------------------------------------------------------------------------
__global__ __launch_bounds__(256, 2)
void gemm1p(const __hip_bfloat16* __restrict__ A, const __hip_bfloat16* __restrict__ Bt,
            const float* __restrict__ bias, __hip_bfloat16* __restrict__ Cout,
            const int* __restrict__ work, const int* __restrict__ wcnt)
{
  extern __shared__ __align__(16) char lds[];
  const int P = wcnt[0] / 24;
  const int x8 = blockIdx.x & 7, l = blockIdx.x >> 3;
  const int p0 = (x8 * P) >> 3;
  const int p1 = ((x8 + 1) * P) >> 3;
  const int px = p1 - p0;
  const int items_x = px * 24;

  const int t = threadIdx.x, wv = t >> 6, lane = t & 63;
  const int wm = wv >> 1, wn = wv & 1;
  const int fr = lane & 15, fk = lane >> 4;
  constexpr int ntk = CDIM / 64;   // 12

  int il = l;
  if (il >= items_x) return;

  int bx = il / px;
  int p  = p0 + (il - bx * px);
  int w  = work[p];
  int e  = w >> 8, by = w & 255;
  const __hip_bfloat16* Ae = A + (size_t)e * CAPC * CDIM + (size_t)by * 128 * CDIM;
  const char* BeT = (const char*)Bt + (((size_t)e * 24 + bx) * 12) * 16384;

  stage_a(Ae, lds, CDIM, 0, wv, lane);
  stage_b(BeT, lds, 0, wv, lane);
  stage_a(Ae, lds, CDIM, 1, wv, lane);
  stage_b(BeT, lds, 1, wv, lane);
  SB0();

  for (; il < items_x; il += 64) {
    floatx4 acc[4][4] = {};

#pragma unroll 1
    for (int kt = 0; kt < ntk - 2; ++kt)
      ktile2<8, true>(kt, lds, Ae, BeT, CDIM, acc, wm, wn, fr, fk, wv, lane);
    ktile2<8, false>(ntk - 2, lds, Ae, BeT, CDIM, acc, wm, wn, fr, fk, wv, lane);
    ktile2<0, false>(ntk - 1, lds, Ae, BeT, CDIM, acc, wm, wn, fr, fk, wv, lane);

    // prefetch next item's first two K-tiles (hides under epilogue VALU)
    const int il2 = il + 64;
    const __hip_bfloat16* Ae2 = Ae; const char* BeT2 = BeT;
    int e2 = e, by2 = by, bx2 = bx;
    if (il2 < items_x) {
      bx2 = il2 / px;
      const int p2 = p0 + (il2 - bx2 * px);
      const int w2 = work[p2];
      e2 = w2 >> 8; by2 = w2 & 255;
      Ae2 = A + (size_t)e2 * CAPC * CDIM + (size_t)by2 * 128 * CDIM;
      BeT2 = (const char*)Bt + (((size_t)e2 * 24 + bx2) * 12) * 16384;
      stage_a(Ae2, lds, CDIM, 0, wv, lane);
      stage_b(BeT2, lds, 0, wv, lane);
      stage_a(Ae2, lds, CDIM, 1, wv, lane);
      stage_b(BeT2, lds, 1, wv, lane);
      SB0();
    }

    epilogue_bf16<1>(acc, lds + 65536,
                     bias + (size_t)e * HDIM,
                     (unsigned short*)Cout + (size_t)e * CAPC * HDIM,
                     HDIM, by * 128, bx * 128, wm, wn, fr, fk, wv, lane);
    __builtin_amdgcn_s_barrier();   // epilogue LDS region free for next item
    SB0();

    Ae = Ae2; BeT = BeT2; e = e2; by = by2; bx = bx2;
  }
}

// ---------------------------------------------------------------------------
// K6b: GEMM2 — single round; B tiled: [e][bx<6][kt<48][128][64].
// ---------------------------------------------------------------------------
__global__ __launch_bounds__(256, 2)
void gemm2x(const __hip_bfloat16* __restrict__ A, const __hip_bfloat16* __restrict__ Bt,
            const float* __restrict__ bias, __hip_bfloat16* __restrict__ Cout,
            const int* __restrict__ work, const int* __restrict__ wcnt)
{
  extern __shared__ __align__(16) char lds[];
  const int T = wcnt[1];
  const int bId = blockIdx.x;
  const int cpx = (T + 7) >> 3;
  if ((bId >> 3) >= cpx) return;
  const int idx = (bId & 7) * cpx + (bId >> 3);
  if (idx >= T) return;
  const int p = idx / 6;
  const int bx0 = idx % 6;
  const int bx = (p & 1) ? (5 - bx0) : bx0;
  const int w = work[p];
  const int e = w >> 8, by = w & 255;

  const int t = threadIdx.x, wv = t >> 6, lane = t & 63;
  const int wm = wv >> 1, wn = wv & 1;
  const int fr = lane & 15, fk = lane >> 4;
  constexpr int ntk = HDIM / 64;   // 48

  const __hip_bfloat16* Ae = A + (size_t)e * CAPC * HDIM + (size_t)by * 128 * HDIM;
  const char* BeT = (const char*)Bt + (((size_t)e * 6 + bx) * 48) * 16384;

  floatx4 acc[4][4] = {};

  stage_a(Ae, lds, HDIM, 0, wv, lane);
  stage_b(BeT, lds, 0, wv, lane);
  stage_a(Ae, lds, HDIM, 1, wv, lane);
  stage_b(BeT, lds, 1, wv, lane);
  SB0();

#pragma unroll 1
  for (int kt = 0; kt < ntk - 2; ++kt)
    ktile2<8, true>(kt, lds, Ae, BeT, HDIM, acc, wm, wn, fr, fk, wv, lane);
  ktile2<8, false>(ntk - 2, lds, Ae, BeT, HDIM, acc, wm, wn, fr, fk, wv, lane);
  ktile2<0, false>(ntk - 1, lds, Ae, BeT, HDIM, acc, wm, wn, fr, fk, wv, lane);

  epilogue_bf16<2>(acc, lds,
                   bias + (size_t)e * CDIM,
                   (unsigned short*)Cout + (size_t)e * CAPC * CDIM,
                   CDIM, by * 128, bx * 128, wm, wn, fr, fk, wv, lane);
}

// ---------------------------------------------------------------------------
// K7: combine — out[n] = w0*exp_out[e0][s0] + w1*exp_out[e1][s1], bf16 eout.
// ---------------------------------------------------------------------------
__global__ __launch_bounds__(256)
void combine_kernel(const __hip_bfloat16* __restrict__ eout, const int* __restrict__ eidx,
                    const float* __restrict__ pval, const int* __restrict__ slot,
                    float* __restrict__ out)
{
  const int wv = threadIdx.x >> 6, lane = threadIdx.x & 63;
  const int n = blockIdx.x * 4 + wv;
  const int e0 = eidx[n], e1 = eidx[N_TOK + n];
  int s0 = slot[n], s1 = slot[N_TOK + n];
  const float w0 = (s0 >= 0) ? pval[n] : 0.f;
  const float w1 = (s1 >= 0) ? pval[N_TOK + n] : 0.f;
  s0 = (s0 >= 0) ? s0 : 0;
  s1 = (s1 >= 0) ? s1 : 0;
  const ushort4* r0 = (const ushort4*)((const unsigned short*)eout + ((size_t)e0 * CAPC + s0) * CDIM);
  const ushort4* r1 = (const ushort4*)((const unsigned short*)eout + ((size_t)e1 * CAPC + s1) * CDIM);
  float4* o = (float4*)(out + (size_t)n * CDIM);
#pragma unroll
  for (int i = 0; i < 3; ++i) {
    const ushort4 a = r0[i * 64 + lane];
    const ushort4 b = r1[i * 64 + lane];
    float4 c;
    c.x = w0 * bf2f(a.x) + w1 * bf2f(b.x);
    c.y = w0 * bf2f(a.y) + w1 * bf2f(b.y);
    c.z = w0 * bf2f(a.z) + w1 * bf2f(b.z);
    c.w = w0 * bf2f(a.w) + w1 * bf2f(b.w);
    o[i * 64 + lane] = c;
  }
}

// ---------------------------------------------------------------------------
extern "C" void kernel_launch(void* const* d_in, const int* in_sizes, int n_in,
                              void* d_out, int out_size, void* d_ws, size_t ws_size,
                              hipStream_t stream)
{
  const float* x   = (const float*)d_in[0];
  const float* wg  = (const float*)d_in[1];
  const float* cfc = (const float*)d_in[2];
  const float* fcb = (const float*)d_in[3];
  const float* cpr = (const float*)d_in[4];
  const float* prb = (const float*)d_in[5];
  float* out = (float*)d_out;

  char* ws = (char*)d_ws;
  size_t off = 0;
  auto take = [&](size_t bytes) -> void* {
    void* p = ws + off;
    off += (bytes + 255) & ~(size_t)255;
    return p;
  };
  __hip_bfloat16* wfcT = (__hip_bfloat16*)take((size_t)E_EXP * HDIM * CDIM * 2);
  __hip_bfloat16* wprT = (__hip_bfloat16*)take((size_t)E_EXP * CDIM * HDIM * 2);
  __hip_bfloat16* xin  = (__hip_bfloat16*)take((size_t)E_EXP * CAPC * CDIM * 2);
  __hip_bfloat16* hbuf = (__hip_bfloat16*)take((size_t)E_EXP * CAPC * HDIM * 2);
  __hip_bfloat16* eout = (__hip_bfloat16*)take((size_t)E_EXP * CAPC * CDIM * 2);
  int*   eidx = (int*)take((size_t)2 * N_TOK * 4);
  float* pv   = (float*)take((size_t)2 * N_TOK * 4);
  int*   slot = (int*)take((size_t)2 * N_TOK * 4);
  int*   stok = (int*)take((size_t)E_EXP * CAPC * 4);
  int*   ecnt = (int*)take((size_t)E_EXP * 4);
  int*   work2 = (int*)take((size_t)128 * 4);
  int*   wcnt = (int*)take((size_t)2 * 4);

  hipFuncSetAttribute((const void*)gemm1p,
                      hipFuncAttributeMaxDynamicSharedMemorySize, 73728);
  hipFuncSetAttribute((const void*)gemm2x,
                      hipFuncAttributeMaxDynamicSharedMemorySize, 65536);

  prep_kernel<<<4608 + 1024, 256, 0, stream>>>(cfc, cpr, wfcT, wprT, x, wg, eidx, pv);
  scan_kernel<<<1, 256, 0, stream>>>(eidx, slot, stok, ecnt, work2, wcnt);
  dispatch_kernel<<<(E_EXP * CAPC) / 4, 256, 0, stream>>>(x, stok, ecnt, xin);

  // GEMM1 + bias + GELU -> h (bf16): persistent, cross-item prefetch, 72KB LDS.
  gemm1p<<<512, 256, 73728, stream>>>(xin, wfcT, fcb, hbuf, work2, wcnt);
  // GEMM2 + bias -> eout (bf16): single round.
  gemm2x<<<768, 256, 65536, stream>>>(hbuf, wprT, prb, eout, work2, wcnt);

  combine_kernel<<<N_TOK / 4, 256, 0, stream>>>(eout, eidx, pv, slot, out);
}